// Round 1
// 615.334 us; speedup vs baseline: 1.0041x; 1.0041x over previous
//
#include <hip/hip_runtime.h>
#include <hip/hip_bf16.h>

// GraphSAGE 3-layer, N=100000, E=1.6M, dims 256->256->128->1.
// R11: remove atomics from fill_csr. prep's degree-count atomicAdd now
// captures its return as rank[e]; fill becomes a pure scatter
// csr[starts[dst]+rank] = src (no atomic round-trip in the hot kernel).
// endoff stays pristine (exclusive starts); aggregators read
// [endoff[i], endoff[i+1]). To make room for rank[] without growing the
// workspace, X1b is eliminated: the L1 GEMM reads x in f32 directly and
// converts to bf16 fragments in-register (same f2b rounding).

typedef __attribute__((ext_vector_type(8))) short short8;
typedef __attribute__((ext_vector_type(4))) float f32x4;

__device__ __forceinline__ unsigned short f2b(float f) {
    __hip_bfloat16 h = __float2bfloat16(f);
    return *reinterpret_cast<unsigned short*>(&h);
}
__device__ __forceinline__ float b2f(unsigned short u) {
    union { unsigned int i; float f; } v; v.i = ((unsigned int)u) << 16; return v.f;
}

// ---- fused prep: prep_w x4 | count_deg + rank capture --------------------
__global__ __launch_bounds__(256) void prep_fused(
    const float* __restrict__ Wl1, const float* __restrict__ Wr1,
    const float* __restrict__ Wl2, const float* __restrict__ Wr2,
    unsigned short* __restrict__ Wl1s, unsigned short* __restrict__ Wr1s,
    unsigned short* __restrict__ Wl2s, unsigned short* __restrict__ Wr2s,
    const int* __restrict__ dst, int* __restrict__ deg,
    int* __restrict__ rank, int E)
{
    const int b = blockIdx.x;
    const int tid = threadIdx.x;
    if (b < 768) {
        const float* W; unsigned short* O; int base, hs;
        if (b < 256)      { W = Wl1; O = Wl1s; base = b;       hs = 8; }
        else if (b < 512) { W = Wr1; O = Wr1s; base = b - 256; hs = 8; }
        else if (b < 640) { W = Wl2; O = Wl2s; base = b - 512; hs = 7; }
        else              { W = Wr2; O = Wr2s; base = b - 640; hs = 7; }
        const int i = base * 256 + tid;
        const int k = i >> hs;
        const int h = i & ((1 << hs) - 1);
        O[((size_t)(((k >> 3) << hs) + h) << 3) + (k & 7)] = f2b(W[i]);
    } else {
        const int e = (b - 768) * 256 + tid;
        if (e < E) rank[e] = atomicAdd(&deg[dst[e]], 1);
    }
}

// ---- scan ----------------------------------------------------------------
__global__ __launch_bounds__(256) void scan_phaseA(int* __restrict__ a,
                                                   int* __restrict__ blockSums, int n) {
    __shared__ int sh[256];
    const int tid = threadIdx.x;
    const int base = blockIdx.x * 1024 + tid * 4;
    int v[4];
    #pragma unroll
    for (int i = 0; i < 4; ++i) v[i] = (base + i < n) ? a[base + i] : 0;
    int tsum = v[0] + v[1] + v[2] + v[3];
    sh[tid] = tsum;
    __syncthreads();
    for (int off = 1; off < 256; off <<= 1) {
        int t = (tid >= off) ? sh[tid - off] : 0;
        __syncthreads();
        sh[tid] += t;
        __syncthreads();
    }
    int run = sh[tid] - tsum;
    #pragma unroll
    for (int i = 0; i < 4; ++i) {
        if (base + i < n) a[base + i] = run;
        run += v[i];
    }
    if (tid == 255) blockSums[blockIdx.x] = sh[255];
}

__global__ __launch_bounds__(256) void scan_phaseB(int* __restrict__ bs, int nb) {
    __shared__ int sh[256];
    const int tid = threadIdx.x;
    int v = (tid < nb) ? bs[tid] : 0;
    sh[tid] = v;
    __syncthreads();
    for (int off = 1; off < 256; off <<= 1) {
        int t = (tid >= off) ? sh[tid - off] : 0;
        __syncthreads();
        sh[tid] += t;
        __syncthreads();
    }
    if (tid < nb) bs[tid] = sh[tid] - v;
}

__global__ __launch_bounds__(256) void scan_phaseC(int* __restrict__ a,
                                                   const int* __restrict__ bs, int n) {
    const int base = blockIdx.x * 1024 + threadIdx.x * 4;
    const int add = bs[blockIdx.x];
    #pragma unroll
    for (int i = 0; i < 4; ++i)
        if (base + i < n) a[base + i] += add;
}

// ---- fused L1 GEMM (f32 A direct) + atomic-free fill_csr -----------------
__global__ __launch_bounds__(256) void gemm_l1_fill(
    const float* __restrict__ Xf,
    const unsigned short* __restrict__ Wsw_l,
    const unsigned short* __restrict__ Wsw_r,
    const float* __restrict__ bias,
    unsigned short* __restrict__ Tout,
    unsigned short* __restrict__ Abase,
    int M,
    const int* __restrict__ src, const int* __restrict__ dst,
    const int* __restrict__ starts, const int* __restrict__ rank,
    int* __restrict__ csr, int E)
{
    const int grp = blockIdx.x / 3;
    const int rem = blockIdx.x - grp * 3;
    const int tid = threadIdx.x;

    if (rem != 0) {                        // fill_csr part: no atomics
        const int e = (grp * 2 + rem - 1) * 256 + tid;
        if (e < E) csr[starts[dst[e]] + rank[e]] = src[e];
        return;
    }

    // gemm part (H = 256), A operand loaded f32 and converted in-register
    const int H = 256;
    const int wid = tid >> 6;
    const int lane = tid & 63;
    const int quad = lane >> 4;
    const int l15 = lane & 15;
    const int col0 = (grp & 3) << 6;
    const int m0 = (grp >> 2) * 128 + wid * 32;

    const float* aptr[2];
    #pragma unroll
    for (int mt = 0; mt < 2; ++mt) {
        int r = m0 + mt * 16 + l15;
        if (r > M - 1) r = M - 1;
        aptr[mt] = Xf + ((size_t)r << 8) + (quad << 3);
    }
    const unsigned short* bptr[8];   // 0..3 = Wl, 4..7 = Wr
    #pragma unroll
    for (int nt = 0; nt < 4; ++nt) {
        const int col = col0 + nt * 16 + l15;
        bptr[nt]     = Wsw_l + (((size_t)quad * H + col) << 3);
        bptr[nt + 4] = Wsw_r + (((size_t)quad * H + col) << 3);
    }

    const f32x4 zero = {0.f, 0.f, 0.f, 0.f};
    f32x4 acc[2][8];
    #pragma unroll
    for (int mt = 0; mt < 2; ++mt)
        #pragma unroll
        for (int nt = 0; nt < 8; ++nt) acc[mt][nt] = zero;

    #pragma unroll 2
    for (int ks = 0; ks < 8; ++ks) {
        short8 af[2], bf[8];
        #pragma unroll
        for (int mt = 0; mt < 2; ++mt) {
            const f32x4 f0 = *(const f32x4*)(aptr[mt] + ks * 32);
            const f32x4 f1 = *(const f32x4*)(aptr[mt] + ks * 32 + 4);
            #pragma unroll
            for (int j = 0; j < 4; ++j) {
                af[mt][j]     = (short)f2b(f0[j]);
                af[mt][j + 4] = (short)f2b(f1[j]);
            }
        }
        #pragma unroll
        for (int nt = 0; nt < 8; ++nt)
            bf[nt] = *(const short8*)(bptr[nt] + (size_t)ks * 32 * H);
        #pragma unroll
        for (int mt = 0; mt < 2; ++mt)
            #pragma unroll
            for (int nt = 0; nt < 8; ++nt)
                acc[mt][nt] = __builtin_amdgcn_mfma_f32_16x16x32_bf16(
                    af[mt], bf[nt], acc[mt][nt], 0, 0, 0);
    }

    #pragma unroll
    for (int nt = 0; nt < 4; ++nt) {
        const int colg = col0 + nt * 16 + l15;
        const float bb = bias[colg];
        #pragma unroll
        for (int mt = 0; mt < 2; ++mt) {
            const int gmb = m0 + mt * 16 + quad * 4;
            #pragma unroll
            for (int r = 0; r < 4; ++r) {
                if (gmb + r < M) {
                    Tout [(size_t)(gmb + r) * H + colg] = f2b(acc[mt][nt][r]);
                    Abase[(size_t)(gmb + r) * H + colg] = f2b(acc[mt][nt + 4][r] + bb);
                }
            }
        }
    }
}

// ---- layer-2 aggregation: half-wave per node, 16B/lane loads -------------
__global__ __launch_bounds__(256) void agg256_b(
    const int* __restrict__ endoff, const int* __restrict__ csr,
    const unsigned short* __restrict__ T,
    const unsigned short* __restrict__ Abase, unsigned short* __restrict__ Xout,
    int N, int E)
{
    const int node = (int)((blockIdx.x * 256 + threadIdx.x) >> 5);
    const int lane = threadIdx.x & 31;
    if (node >= N) return;
    const int beg = endoff[node];
    const int end = (node + 1 < N) ? endoff[node + 1] : E;
    float s[8] = {0.f, 0.f, 0.f, 0.f, 0.f, 0.f, 0.f, 0.f};
    int p = beg;
    for (; p + 4 <= end; p += 4) {
        const int a = csr[p], b = csr[p + 1], c = csr[p + 2], d = csr[p + 3];
        const short8 v0 = *(const short8*)(T + ((size_t)a << 8) + (lane << 3));
        const short8 v1 = *(const short8*)(T + ((size_t)b << 8) + (lane << 3));
        const short8 v2 = *(const short8*)(T + ((size_t)c << 8) + (lane << 3));
        const short8 v3 = *(const short8*)(T + ((size_t)d << 8) + (lane << 3));
        #pragma unroll
        for (int j = 0; j < 8; ++j)
            s[j] += (b2f((unsigned short)v0[j]) + b2f((unsigned short)v1[j]))
                  + (b2f((unsigned short)v2[j]) + b2f((unsigned short)v3[j]));
    }
    for (; p < end; ++p) {
        const short8 v = *(const short8*)(T + ((size_t)csr[p] << 8) + (lane << 3));
        #pragma unroll
        for (int j = 0; j < 8; ++j) s[j] += b2f((unsigned short)v[j]);
    }
    const float w = 1.0f / fmaxf((float)(end - beg), 1.0f);
    const short8 bu = *(const short8*)(Abase + ((size_t)node << 8) + (lane << 3));
    short8 o;
    #pragma unroll
    for (int j = 0; j < 8; ++j)
        o[j] = (short)f2b(fmaxf(b2f((unsigned short)bu[j]) + s[j] * w, 0.f));
    *(short8*)(Xout + ((size_t)node << 8) + (lane << 3)) = o;
}

// ---- standalone L2 GEMM (H=128, K=256) -----------------------------------
__global__ __launch_bounds__(256) void gemm_bf16(
    const unsigned short* __restrict__ Xb,
    const unsigned short* __restrict__ Wsw_l,
    const unsigned short* __restrict__ Wsw_r,
    const float* __restrict__ bias,
    unsigned short* __restrict__ Tout,
    unsigned short* __restrict__ Abase,
    int M, int H)
{
    const int tid = threadIdx.x;
    const int wid = tid >> 6;
    const int lane = tid & 63;
    const int quad = lane >> 4;
    const int l15 = lane & 15;

    const int col0 = blockIdx.x << 6;
    const int m0 = blockIdx.y * 128 + wid * 32;

    const unsigned short* aptr[2];
    #pragma unroll
    for (int mt = 0; mt < 2; ++mt) {
        int r = m0 + mt * 16 + l15;
        if (r > M - 1) r = M - 1;
        aptr[mt] = Xb + ((size_t)r << 8) + (quad << 3);
    }
    const unsigned short* bptr[8];
    #pragma unroll
    for (int nt = 0; nt < 4; ++nt) {
        const int col = col0 + nt * 16 + l15;
        bptr[nt]     = Wsw_l + (((size_t)quad * H + col) << 3);
        bptr[nt + 4] = Wsw_r + (((size_t)quad * H + col) << 3);
    }

    const f32x4 zero = {0.f, 0.f, 0.f, 0.f};
    f32x4 acc[2][8];
    #pragma unroll
    for (int mt = 0; mt < 2; ++mt)
        #pragma unroll
        for (int nt = 0; nt < 8; ++nt) acc[mt][nt] = zero;

    #pragma unroll 2
    for (int ks = 0; ks < 8; ++ks) {
        short8 af[2], bf[8];
        #pragma unroll
        for (int mt = 0; mt < 2; ++mt)
            af[mt] = *(const short8*)(aptr[mt] + ks * 32);
        #pragma unroll
        for (int nt = 0; nt < 8; ++nt)
            bf[nt] = *(const short8*)(bptr[nt] + (size_t)ks * 32 * H);
        #pragma unroll
        for (int mt = 0; mt < 2; ++mt)
            #pragma unroll
            for (int nt = 0; nt < 8; ++nt)
                acc[mt][nt] = __builtin_amdgcn_mfma_f32_16x16x32_bf16(
                    af[mt], bf[nt], acc[mt][nt], 0, 0, 0);
    }

    #pragma unroll
    for (int nt = 0; nt < 4; ++nt) {
        const int colg = col0 + nt * 16 + l15;
        const float bb = bias[colg];
        #pragma unroll
        for (int mt = 0; mt < 2; ++mt) {
            const int gmb = m0 + mt * 16 + quad * 4;
            #pragma unroll
            for (int r = 0; r < 4; ++r) {
                if (gmb + r < M) {
                    Tout [(size_t)(gmb + r) * H + colg] = f2b(acc[mt][nt][r]);
                    Abase[(size_t)(gmb + r) * H + colg] = f2b(acc[mt][nt + 4][r] + bb);
                }
            }
        }
    }
}

// ---- fused layer-3: agg128 + gemv (register-resident h2) -----------------
__global__ __launch_bounds__(256) void agg_gemv3(
    const int* __restrict__ endoff, const int* __restrict__ csr,
    const unsigned short* __restrict__ T, const unsigned short* __restrict__ Ab,
    const float* __restrict__ Wl, const float* __restrict__ Wr,
    const float* __restrict__ b,
    float* __restrict__ t3, float* __restrict__ out, int N, int E)
{
    const int node = (int)((blockIdx.x * 256 + threadIdx.x) >> 5);
    const int lane = threadIdx.x & 31;
    if (node >= N) return;
    const int beg = endoff[node];
    const int end = (node + 1 < N) ? endoff[node + 1] : E;
    float s0 = 0.f, s1 = 0.f, s2 = 0.f, s3 = 0.f;
    int p = beg;
    for (; p + 4 <= end; p += 4) {
        const int a = csr[p], bb = csr[p + 1], c = csr[p + 2], d = csr[p + 3];
        ushort4 v0 = *(const ushort4*)(T + ((size_t)a << 7) + (lane << 2));
        ushort4 v1 = *(const ushort4*)(T + ((size_t)bb << 7) + (lane << 2));
        ushort4 v2 = *(const ushort4*)(T + ((size_t)c << 7) + (lane << 2));
        ushort4 v3 = *(const ushort4*)(T + ((size_t)d << 7) + (lane << 2));
        s0 += (b2f(v0.x) + b2f(v1.x)) + (b2f(v2.x) + b2f(v3.x));
        s1 += (b2f(v0.y) + b2f(v1.y)) + (b2f(v2.y) + b2f(v3.y));
        s2 += (b2f(v0.z) + b2f(v1.z)) + (b2f(v2.z) + b2f(v3.z));
        s3 += (b2f(v0.w) + b2f(v1.w)) + (b2f(v2.w) + b2f(v3.w));
    }
    for (; p < end; ++p) {
        ushort4 v = *(const ushort4*)(T + ((size_t)csr[p] << 7) + (lane << 2));
        s0 += b2f(v.x); s1 += b2f(v.y); s2 += b2f(v.z); s3 += b2f(v.w);
    }
    const float w = 1.0f / fmaxf((float)(end - beg), 1.0f);
    const ushort4 bu = *(const ushort4*)(Ab + ((size_t)node << 7) + (lane << 2));
    const float h0 = fmaxf(b2f(bu.x) + s0 * w, 0.f);
    const float h1 = fmaxf(b2f(bu.y) + s1 * w, 0.f);
    const float h2 = fmaxf(b2f(bu.z) + s2 * w, 0.f);
    const float h3 = fmaxf(b2f(bu.w) + s3 * w, 0.f);

    const float4 wl = *(const float4*)(Wl + (lane << 2));
    const float4 wr = *(const float4*)(Wr + (lane << 2));
    float dl = h0 * wl.x + h1 * wl.y + h2 * wl.z + h3 * wl.w;
    float dr = h0 * wr.x + h1 * wr.y + h2 * wr.z + h3 * wr.w;
    #pragma unroll
    for (int off = 16; off > 0; off >>= 1) {
        dl += __shfl_down(dl, off, 64);
        dr += __shfl_down(dr, off, 64);
    }
    if (lane == 0) {
        t3[node] = dl;
        out[node] = dr + b[0];
    }
}

__global__ __launch_bounds__(256) void agg1(
    const int* __restrict__ endoff, const int* __restrict__ csr,
    const float* __restrict__ t3, float* __restrict__ out, int N, int E)
{
    const int i = blockIdx.x * blockDim.x + threadIdx.x;
    if (i >= N) return;
    const int beg = endoff[i];
    const int end = (i + 1 < N) ? endoff[i + 1] : E;
    int p = beg;
    float s = 0.f;
    for (; p + 4 <= end; p += 4)
        s += (t3[csr[p]] + t3[csr[p + 1]]) + (t3[csr[p + 2]] + t3[csr[p + 3]]);
    for (; p < end; ++p) s += t3[csr[p]];
    out[i] += s / fmaxf((float)(end - beg), 1.0f);
}

extern "C" void kernel_launch(void* const* d_in, const int* in_sizes, int n_in,
                              void* d_out, int out_size, void* d_ws, size_t ws_size,
                              hipStream_t stream) {
    const float* x   = (const float*)d_in[0];
    const int*   ei  = (const int*)d_in[1];
    const float* Wl1 = (const float*)d_in[2];
    const float* bl1 = (const float*)d_in[3];
    const float* Wr1 = (const float*)d_in[4];
    const float* Wl2 = (const float*)d_in[5];
    const float* bl2 = (const float*)d_in[6];
    const float* Wr2 = (const float*)d_in[7];
    const float* Wl3 = (const float*)d_in[8];
    const float* bl3 = (const float*)d_in[9];
    const float* Wr3 = (const float*)d_in[10];
    float* out = (float*)d_out;

    const int N = in_sizes[0] / 256;   // 100000
    const int E = in_sizes[1] / 2;     // 1600000
    const int* src = ei;
    const int* dst = ei + E;

    // ---- workspace layout, race-free aliasing ----------------------------
    //   prep:       W rank[0,6.4) deg            (regions 2,3 dead)
    //   scan:       RW endoff(=deg)
    //   L1+fill:    R x(f32), rank, starts       W T1b[51.2,102.4) A1b[102.4,153.6) csr
    //   agg256_b:   R T1b,A1b,csr                W X2b[0,51.2)        (rank dead)
    //   gemm_l2:    R X2b                        W T2b[51.2,76.8) A2b[76.8,102.4)
    //   agg_gemv3:  R T2b,A2b,csr                W t3,out             (X2b dead)
    //   agg1:       R t3,csr                     RW out
    char* W = (char*)d_ws;
    const size_t MB512 = (size_t)100000 * 512;   // 51.2MB
    int* rank = (int*)(W);                       // [0, 6.4MB), dead after L1 fill
    unsigned short* T1b = (unsigned short*)(W + MB512);
    unsigned short* A1b = (unsigned short*)(W + 2 * MB512);
    unsigned short* X2b = (unsigned short*)(W);                  // over dead rank
    unsigned short* T2b = (unsigned short*)(W + MB512);          // over dead T1b
    unsigned short* A2b = (unsigned short*)(W + MB512 + MB512 / 2);
    char* S = W + 3 * MB512;                     // smalls @ 153.6M
    int*   endoff = (int*)(S);
    int*   bsums  = (int*)(S + (size_t)N * 4);
    float* t3     = (float*)(S + (size_t)N * 4 + 1024);
    int*   csr    = (int*)(S + (size_t)N * 8 + 1024);
    unsigned short* Wl1s = (unsigned short*)(S + (size_t)N * 8 + 1024 + (size_t)E * 4);
    unsigned short* Wr1s = Wl1s + 65536;
    unsigned short* Wl2s = Wr1s + 65536;
    unsigned short* Wr2s = Wl2s + 32768;

    // ---- prep: W conversions + degree count w/ rank capture ----
    hipMemsetAsync(endoff, 0, (size_t)N * sizeof(int), stream);
    prep_fused<<<768 + (E + 255) / 256, 256, 0, stream>>>(Wl1, Wr1, Wl2, Wr2,
                                                          Wl1s, Wr1s, Wl2s, Wr2s,
                                                          dst, endoff, rank, E);
    const int nScanBlocks = (N + 1023) / 1024;
    scan_phaseA<<<nScanBlocks, 256, 0, stream>>>(endoff, bsums, N);
    scan_phaseB<<<1, 256, 0, stream>>>(bsums, nScanBlocks);
    scan_phaseC<<<nScanBlocks, 256, 0, stream>>>(endoff, bsums, N);

    // ---- Layer 1 GEMM (f32 A direct) fused with atomic-free fill_csr ----
    gemm_l1_fill<<<3128 * 3, 256, 0, stream>>>(x, Wl1s, Wr1s, bl1, T1b, A1b, N,
                                               src, dst, endoff, rank, csr, E);

    // ---- Layer 2: gather (half-wave/node) then GEMM ----
    agg256_b<<<(N * 32 + 255) / 256, 256, 0, stream>>>(endoff, csr, T1b, A1b, X2b, N, E);
    gemm_bf16<<<dim3(2, (N + 127) / 128), 256, 0, stream>>>(X2b, Wl2s, Wr2s, bl2,
                                                            T2b, A2b, N, 128);

    // ---- Layer 3: fused agg128 + gemv, then final scalar aggregation ----
    agg_gemv3<<<(N * 32 + 255) / 256, 256, 0, stream>>>(endoff, csr, T2b, A2b,
                                                        Wl3, Wr3, bl3, t3, out, N, E);
    agg1<<<(N + 255) / 256, 256, 0, stream>>>(endoff, csr, t3, out, N, E);
}

// Round 2
// 614.755 us; speedup vs baseline: 1.0051x; 1.0009x over previous
//
#include <hip/hip_runtime.h>
#include <hip/hip_bf16.h>

// GraphSAGE 3-layer, N=100000, E=1.6M, dims 256->256->128->1.
// R12: combine R10's bf16 X1b A-operand (compact fetch, L2 absorbs the
// 4x column-block re-read) with R11's atomic-free fill (rank captured in
// prep's degree-count atomicAdd). rank stored as ushort (max degree on
// this random graph << 65536), appended after weight buffers: peak
// workspace ~164.4 MB. endoff stays pristine exclusive-starts;
// aggregators read [endoff[i], endoff[i+1]).

typedef __attribute__((ext_vector_type(8))) short short8;
typedef __attribute__((ext_vector_type(4))) float f32x4;

__device__ __forceinline__ unsigned short f2b(float f) {
    __hip_bfloat16 h = __float2bfloat16(f);
    return *reinterpret_cast<unsigned short*>(&h);
}
__device__ __forceinline__ float b2f(unsigned short u) {
    union { unsigned int i; float f; } v; v.i = ((unsigned int)u) << 16; return v.f;
}

// ---- fused prep: convert_x | prep_w x4 | count_deg + rank capture --------
__global__ __launch_bounds__(256) void prep_fused(
    const float* __restrict__ x, unsigned short* __restrict__ xb,
    const float* __restrict__ Wl1, const float* __restrict__ Wr1,
    const float* __restrict__ Wl2, const float* __restrict__ Wr2,
    unsigned short* __restrict__ Wl1s, unsigned short* __restrict__ Wr1s,
    unsigned short* __restrict__ Wl2s, unsigned short* __restrict__ Wr2s,
    const int* __restrict__ dst, int* __restrict__ deg,
    unsigned short* __restrict__ rank, int E)
{
    const int b = blockIdx.x;
    const int tid = threadIdx.x;
    if (b < 25000) {
        const int i = b * 256 + tid;
        float4 v = *(const float4*)(x + (size_t)i * 4);
        ushort4 o;
        o.x = f2b(v.x); o.y = f2b(v.y); o.z = f2b(v.z); o.w = f2b(v.w);
        *(ushort4*)(xb + (size_t)i * 4) = o;
    } else if (b < 25768) {
        const float* W; unsigned short* O; int base, hs;
        if (b < 25256)      { W = Wl1; O = Wl1s; base = b - 25000; hs = 8; }
        else if (b < 25512) { W = Wr1; O = Wr1s; base = b - 25256; hs = 8; }
        else if (b < 25640) { W = Wl2; O = Wl2s; base = b - 25512; hs = 7; }
        else                { W = Wr2; O = Wr2s; base = b - 25640; hs = 7; }
        const int i = base * 256 + tid;
        const int k = i >> hs;
        const int h = i & ((1 << hs) - 1);
        O[((size_t)(((k >> 3) << hs) + h) << 3) + (k & 7)] = f2b(W[i]);
    } else {
        const int e = (b - 25768) * 256 + tid;
        if (e < E) rank[e] = (unsigned short)atomicAdd(&deg[dst[e]], 1);
    }
}

// ---- scan ----------------------------------------------------------------
__global__ __launch_bounds__(256) void scan_phaseA(int* __restrict__ a,
                                                   int* __restrict__ blockSums, int n) {
    __shared__ int sh[256];
    const int tid = threadIdx.x;
    const int base = blockIdx.x * 1024 + tid * 4;
    int v[4];
    #pragma unroll
    for (int i = 0; i < 4; ++i) v[i] = (base + i < n) ? a[base + i] : 0;
    int tsum = v[0] + v[1] + v[2] + v[3];
    sh[tid] = tsum;
    __syncthreads();
    for (int off = 1; off < 256; off <<= 1) {
        int t = (tid >= off) ? sh[tid - off] : 0;
        __syncthreads();
        sh[tid] += t;
        __syncthreads();
    }
    int run = sh[tid] - tsum;
    #pragma unroll
    for (int i = 0; i < 4; ++i) {
        if (base + i < n) a[base + i] = run;
        run += v[i];
    }
    if (tid == 255) blockSums[blockIdx.x] = sh[255];
}

__global__ __launch_bounds__(256) void scan_phaseB(int* __restrict__ bs, int nb) {
    __shared__ int sh[256];
    const int tid = threadIdx.x;
    int v = (tid < nb) ? bs[tid] : 0;
    sh[tid] = v;
    __syncthreads();
    for (int off = 1; off < 256; off <<= 1) {
        int t = (tid >= off) ? sh[tid - off] : 0;
        __syncthreads();
        sh[tid] += t;
        __syncthreads();
    }
    if (tid < nb) bs[tid] = sh[tid] - v;
}

__global__ __launch_bounds__(256) void scan_phaseC(int* __restrict__ a,
                                                   const int* __restrict__ bs, int n) {
    const int base = blockIdx.x * 1024 + threadIdx.x * 4;
    const int add = bs[blockIdx.x];
    #pragma unroll
    for (int i = 0; i < 4; ++i)
        if (base + i < n) a[base + i] += add;
}

// ---- fused L1 GEMM (bf16 A) + atomic-free fill_csr -----------------------
__global__ __launch_bounds__(256) void gemm_l1_fill(
    const unsigned short* __restrict__ Xb,
    const unsigned short* __restrict__ Wsw_l,
    const unsigned short* __restrict__ Wsw_r,
    const float* __restrict__ bias,
    unsigned short* __restrict__ Tout,
    unsigned short* __restrict__ Abase,
    int M,
    const int* __restrict__ src, const int* __restrict__ dst,
    const int* __restrict__ starts, const unsigned short* __restrict__ rank,
    int* __restrict__ csr, int E)
{
    const int grp = blockIdx.x / 3;
    const int rem = blockIdx.x - grp * 3;
    const int tid = threadIdx.x;

    if (rem != 0) {                        // fill_csr part: no atomics
        const int e = (grp * 2 + rem - 1) * 256 + tid;
        if (e < E) csr[starts[dst[e]] + (int)rank[e]] = src[e];
        return;
    }

    // gemm part (H = 256)
    const int H = 256;
    const int wid = tid >> 6;
    const int lane = tid & 63;
    const int quad = lane >> 4;
    const int l15 = lane & 15;
    const int col0 = (grp & 3) << 6;
    const int m0 = (grp >> 2) * 128 + wid * 32;

    const unsigned short* aptr[2];
    #pragma unroll
    for (int mt = 0; mt < 2; ++mt) {
        int r = m0 + mt * 16 + l15;
        if (r > M - 1) r = M - 1;
        aptr[mt] = Xb + ((size_t)r << 8) + (quad << 3);
    }
    const unsigned short* bptr[8];   // 0..3 = Wl, 4..7 = Wr
    #pragma unroll
    for (int nt = 0; nt < 4; ++nt) {
        const int col = col0 + nt * 16 + l15;
        bptr[nt]     = Wsw_l + (((size_t)quad * H + col) << 3);
        bptr[nt + 4] = Wsw_r + (((size_t)quad * H + col) << 3);
    }

    const f32x4 zero = {0.f, 0.f, 0.f, 0.f};
    f32x4 acc[2][8];
    #pragma unroll
    for (int mt = 0; mt < 2; ++mt)
        #pragma unroll
        for (int nt = 0; nt < 8; ++nt) acc[mt][nt] = zero;

    #pragma unroll 2
    for (int ks = 0; ks < 8; ++ks) {
        short8 af[2], bf[8];
        #pragma unroll
        for (int mt = 0; mt < 2; ++mt)
            af[mt] = *(const short8*)(aptr[mt] + ks * 32);
        #pragma unroll
        for (int nt = 0; nt < 8; ++nt)
            bf[nt] = *(const short8*)(bptr[nt] + (size_t)ks * 32 * H);
        #pragma unroll
        for (int mt = 0; mt < 2; ++mt)
            #pragma unroll
            for (int nt = 0; nt < 8; ++nt)
                acc[mt][nt] = __builtin_amdgcn_mfma_f32_16x16x32_bf16(
                    af[mt], bf[nt], acc[mt][nt], 0, 0, 0);
    }

    #pragma unroll
    for (int nt = 0; nt < 4; ++nt) {
        const int colg = col0 + nt * 16 + l15;
        const float bb = bias[colg];
        #pragma unroll
        for (int mt = 0; mt < 2; ++mt) {
            const int gmb = m0 + mt * 16 + quad * 4;
            #pragma unroll
            for (int r = 0; r < 4; ++r) {
                if (gmb + r < M) {
                    Tout [(size_t)(gmb + r) * H + colg] = f2b(acc[mt][nt][r]);
                    Abase[(size_t)(gmb + r) * H + colg] = f2b(acc[mt][nt + 4][r] + bb);
                }
            }
        }
    }
}

// ---- layer-2 aggregation: half-wave per node, 16B/lane loads -------------
__global__ __launch_bounds__(256) void agg256_b(
    const int* __restrict__ endoff, const int* __restrict__ csr,
    const unsigned short* __restrict__ T,
    const unsigned short* __restrict__ Abase, unsigned short* __restrict__ Xout,
    int N, int E)
{
    const int node = (int)((blockIdx.x * 256 + threadIdx.x) >> 5);
    const int lane = threadIdx.x & 31;
    if (node >= N) return;
    const int beg = endoff[node];
    const int end = (node + 1 < N) ? endoff[node + 1] : E;
    float s[8] = {0.f, 0.f, 0.f, 0.f, 0.f, 0.f, 0.f, 0.f};
    int p = beg;
    for (; p + 4 <= end; p += 4) {
        const int a = csr[p], b = csr[p + 1], c = csr[p + 2], d = csr[p + 3];
        const short8 v0 = *(const short8*)(T + ((size_t)a << 8) + (lane << 3));
        const short8 v1 = *(const short8*)(T + ((size_t)b << 8) + (lane << 3));
        const short8 v2 = *(const short8*)(T + ((size_t)c << 8) + (lane << 3));
        const short8 v3 = *(const short8*)(T + ((size_t)d << 8) + (lane << 3));
        #pragma unroll
        for (int j = 0; j < 8; ++j)
            s[j] += (b2f((unsigned short)v0[j]) + b2f((unsigned short)v1[j]))
                  + (b2f((unsigned short)v2[j]) + b2f((unsigned short)v3[j]));
    }
    for (; p < end; ++p) {
        const short8 v = *(const short8*)(T + ((size_t)csr[p] << 8) + (lane << 3));
        #pragma unroll
        for (int j = 0; j < 8; ++j) s[j] += b2f((unsigned short)v[j]);
    }
    const float w = 1.0f / fmaxf((float)(end - beg), 1.0f);
    const short8 bu = *(const short8*)(Abase + ((size_t)node << 8) + (lane << 3));
    short8 o;
    #pragma unroll
    for (int j = 0; j < 8; ++j)
        o[j] = (short)f2b(fmaxf(b2f((unsigned short)bu[j]) + s[j] * w, 0.f));
    *(short8*)(Xout + ((size_t)node << 8) + (lane << 3)) = o;
}

// ---- standalone L2 GEMM (H=128, K=256) -----------------------------------
__global__ __launch_bounds__(256) void gemm_bf16(
    const unsigned short* __restrict__ Xb,
    const unsigned short* __restrict__ Wsw_l,
    const unsigned short* __restrict__ Wsw_r,
    const float* __restrict__ bias,
    unsigned short* __restrict__ Tout,
    unsigned short* __restrict__ Abase,
    int M, int H)
{
    const int tid = threadIdx.x;
    const int wid = tid >> 6;
    const int lane = tid & 63;
    const int quad = lane >> 4;
    const int l15 = lane & 15;

    const int col0 = blockIdx.x << 6;
    const int m0 = blockIdx.y * 128 + wid * 32;

    const unsigned short* aptr[2];
    #pragma unroll
    for (int mt = 0; mt < 2; ++mt) {
        int r = m0 + mt * 16 + l15;
        if (r > M - 1) r = M - 1;
        aptr[mt] = Xb + ((size_t)r << 8) + (quad << 3);
    }
    const unsigned short* bptr[8];
    #pragma unroll
    for (int nt = 0; nt < 4; ++nt) {
        const int col = col0 + nt * 16 + l15;
        bptr[nt]     = Wsw_l + (((size_t)quad * H + col) << 3);
        bptr[nt + 4] = Wsw_r + (((size_t)quad * H + col) << 3);
    }

    const f32x4 zero = {0.f, 0.f, 0.f, 0.f};
    f32x4 acc[2][8];
    #pragma unroll
    for (int mt = 0; mt < 2; ++mt)
        #pragma unroll
        for (int nt = 0; nt < 8; ++nt) acc[mt][nt] = zero;

    #pragma unroll 2
    for (int ks = 0; ks < 8; ++ks) {
        short8 af[2], bf[8];
        #pragma unroll
        for (int mt = 0; mt < 2; ++mt)
            af[mt] = *(const short8*)(aptr[mt] + ks * 32);
        #pragma unroll
        for (int nt = 0; nt < 8; ++nt)
            bf[nt] = *(const short8*)(bptr[nt] + (size_t)ks * 32 * H);
        #pragma unroll
        for (int mt = 0; mt < 2; ++mt)
            #pragma unroll
            for (int nt = 0; nt < 8; ++nt)
                acc[mt][nt] = __builtin_amdgcn_mfma_f32_16x16x32_bf16(
                    af[mt], bf[nt], acc[mt][nt], 0, 0, 0);
    }

    #pragma unroll
    for (int nt = 0; nt < 4; ++nt) {
        const int colg = col0 + nt * 16 + l15;
        const float bb = bias[colg];
        #pragma unroll
        for (int mt = 0; mt < 2; ++mt) {
            const int gmb = m0 + mt * 16 + quad * 4;
            #pragma unroll
            for (int r = 0; r < 4; ++r) {
                if (gmb + r < M) {
                    Tout [(size_t)(gmb + r) * H + colg] = f2b(acc[mt][nt][r]);
                    Abase[(size_t)(gmb + r) * H + colg] = f2b(acc[mt][nt + 4][r] + bb);
                }
            }
        }
    }
}

// ---- fused layer-3: agg128 + gemv (register-resident h2) -----------------
__global__ __launch_bounds__(256) void agg_gemv3(
    const int* __restrict__ endoff, const int* __restrict__ csr,
    const unsigned short* __restrict__ T, const unsigned short* __restrict__ Ab,
    const float* __restrict__ Wl, const float* __restrict__ Wr,
    const float* __restrict__ b,
    float* __restrict__ t3, float* __restrict__ out, int N, int E)
{
    const int node = (int)((blockIdx.x * 256 + threadIdx.x) >> 5);
    const int lane = threadIdx.x & 31;
    if (node >= N) return;
    const int beg = endoff[node];
    const int end = (node + 1 < N) ? endoff[node + 1] : E;
    float s0 = 0.f, s1 = 0.f, s2 = 0.f, s3 = 0.f;
    int p = beg;
    for (; p + 4 <= end; p += 4) {
        const int a = csr[p], bb = csr[p + 1], c = csr[p + 2], d = csr[p + 3];
        ushort4 v0 = *(const ushort4*)(T + ((size_t)a << 7) + (lane << 2));
        ushort4 v1 = *(const ushort4*)(T + ((size_t)bb << 7) + (lane << 2));
        ushort4 v2 = *(const ushort4*)(T + ((size_t)c << 7) + (lane << 2));
        ushort4 v3 = *(const ushort4*)(T + ((size_t)d << 7) + (lane << 2));
        s0 += (b2f(v0.x) + b2f(v1.x)) + (b2f(v2.x) + b2f(v3.x));
        s1 += (b2f(v0.y) + b2f(v1.y)) + (b2f(v2.y) + b2f(v3.y));
        s2 += (b2f(v0.z) + b2f(v1.z)) + (b2f(v2.z) + b2f(v3.z));
        s3 += (b2f(v0.w) + b2f(v1.w)) + (b2f(v2.w) + b2f(v3.w));
    }
    for (; p < end; ++p) {
        ushort4 v = *(const ushort4*)(T + ((size_t)csr[p] << 7) + (lane << 2));
        s0 += b2f(v.x); s1 += b2f(v.y); s2 += b2f(v.z); s3 += b2f(v.w);
    }
    const float w = 1.0f / fmaxf((float)(end - beg), 1.0f);
    const ushort4 bu = *(const ushort4*)(Ab + ((size_t)node << 7) + (lane << 2));
    const float h0 = fmaxf(b2f(bu.x) + s0 * w, 0.f);
    const float h1 = fmaxf(b2f(bu.y) + s1 * w, 0.f);
    const float h2 = fmaxf(b2f(bu.z) + s2 * w, 0.f);
    const float h3 = fmaxf(b2f(bu.w) + s3 * w, 0.f);

    const float4 wl = *(const float4*)(Wl + (lane << 2));
    const float4 wr = *(const float4*)(Wr + (lane << 2));
    float dl = h0 * wl.x + h1 * wl.y + h2 * wl.z + h3 * wl.w;
    float dr = h0 * wr.x + h1 * wr.y + h2 * wr.z + h3 * wr.w;
    #pragma unroll
    for (int off = 16; off > 0; off >>= 1) {
        dl += __shfl_down(dl, off, 64);
        dr += __shfl_down(dr, off, 64);
    }
    if (lane == 0) {
        t3[node] = dl;
        out[node] = dr + b[0];
    }
}

__global__ __launch_bounds__(256) void agg1(
    const int* __restrict__ endoff, const int* __restrict__ csr,
    const float* __restrict__ t3, float* __restrict__ out, int N, int E)
{
    const int i = blockIdx.x * blockDim.x + threadIdx.x;
    if (i >= N) return;
    const int beg = endoff[i];
    const int end = (i + 1 < N) ? endoff[i + 1] : E;
    int p = beg;
    float s = 0.f;
    for (; p + 4 <= end; p += 4)
        s += (t3[csr[p]] + t3[csr[p + 1]]) + (t3[csr[p + 2]] + t3[csr[p + 3]]);
    for (; p < end; ++p) s += t3[csr[p]];
    out[i] += s / fmaxf((float)(end - beg), 1.0f);
}

extern "C" void kernel_launch(void* const* d_in, const int* in_sizes, int n_in,
                              void* d_out, int out_size, void* d_ws, size_t ws_size,
                              hipStream_t stream) {
    const float* x   = (const float*)d_in[0];
    const int*   ei  = (const int*)d_in[1];
    const float* Wl1 = (const float*)d_in[2];
    const float* bl1 = (const float*)d_in[3];
    const float* Wr1 = (const float*)d_in[4];
    const float* Wl2 = (const float*)d_in[5];
    const float* bl2 = (const float*)d_in[6];
    const float* Wr2 = (const float*)d_in[7];
    const float* Wl3 = (const float*)d_in[8];
    const float* bl3 = (const float*)d_in[9];
    const float* Wr3 = (const float*)d_in[10];
    float* out = (float*)d_out;

    const int N = in_sizes[0] / 256;   // 100000
    const int E = in_sizes[1] / 2;     // 1600000
    const int* src = ei;
    const int* dst = ei + E;

    // ---- workspace layout, race-free aliasing ----------------------------
    //   prep:       W X1b[0,51.2), rank(us), deg
    //   scan:       RW endoff(=deg)
    //   L1+fill:    R X1b, rank, starts         W T1b[51.2,102.4) A1b[102.4,153.6) csr
    //   agg256_b:   R T1b,A1b,csr               W X2b[0,51.2)        (X1b, rank dead)
    //   gemm_l2:    R X2b                       W T2b[51.2,76.8) A2b[76.8,102.4)
    //   agg_gemv3:  R T2b,A2b,csr               W t3,out             (X2b dead)
    //   agg1:       R t3,csr                    RW out
    char* W = (char*)d_ws;
    const size_t MB512 = (size_t)100000 * 512;   // 51.2MB
    unsigned short* X1b = (unsigned short*)(W);
    unsigned short* T1b = (unsigned short*)(W + MB512);
    unsigned short* A1b = (unsigned short*)(W + 2 * MB512);
    unsigned short* X2b = (unsigned short*)(W);                  // over dead X1b
    unsigned short* T2b = (unsigned short*)(W + MB512);          // over dead T1b
    unsigned short* A2b = (unsigned short*)(W + MB512 + MB512 / 2);
    char* S = W + 3 * MB512;                     // smalls @ 153.6M
    int*   endoff = (int*)(S);
    int*   bsums  = (int*)(S + (size_t)N * 4);
    float* t3     = (float*)(S + (size_t)N * 4 + 1024);
    int*   csr    = (int*)(S + (size_t)N * 8 + 1024);
    unsigned short* Wl1s = (unsigned short*)(S + (size_t)N * 8 + 1024 + (size_t)E * 4);
    unsigned short* Wr1s = Wl1s + 65536;
    unsigned short* Wl2s = Wr1s + 65536;
    unsigned short* Wr2s = Wl2s + 32768;
    unsigned short* rank = Wr2s + 32768;         // ushort[E], +3.2MB

    // ---- prep: fused conversions + degree count w/ rank capture ----
    hipMemsetAsync(endoff, 0, (size_t)N * sizeof(int), stream);
    prep_fused<<<25768 + (E + 255) / 256, 256, 0, stream>>>(
        x, X1b, Wl1, Wr1, Wl2, Wr2, Wl1s, Wr1s, Wl2s, Wr2s,
        dst, endoff, rank, E);
    const int nScanBlocks = (N + 1023) / 1024;
    scan_phaseA<<<nScanBlocks, 256, 0, stream>>>(endoff, bsums, N);
    scan_phaseB<<<1, 256, 0, stream>>>(bsums, nScanBlocks);
    scan_phaseC<<<nScanBlocks, 256, 0, stream>>>(endoff, bsums, N);

    // ---- Layer 1 GEMM (bf16 A) fused with atomic-free fill_csr ----
    gemm_l1_fill<<<3128 * 3, 256, 0, stream>>>(X1b, Wl1s, Wr1s, bl1, T1b, A1b, N,
                                               src, dst, endoff, rank, csr, E);

    // ---- Layer 2: gather (half-wave/node) then GEMM ----
    agg256_b<<<(N * 32 + 255) / 256, 256, 0, stream>>>(endoff, csr, T1b, A1b, X2b, N, E);
    gemm_bf16<<<dim3(2, (N + 127) / 128), 256, 0, stream>>>(X2b, Wl2s, Wr2s, bl2,
                                                            T2b, A2b, N, 128);

    // ---- Layer 3: fused agg128 + gemv, then final scalar aggregation ----
    agg_gemv3<<<(N * 32 + 255) / 256, 256, 0, stream>>>(endoff, csr, T2b, A2b,
                                                        Wl3, Wr3, bl3, t3, out, N, E);
    agg1<<<(N + 255) / 256, 256, 0, stream>>>(endoff, csr, t3, out, N, E);
}

// Round 3
// 570.092 us; speedup vs baseline: 1.0838x; 1.0783x over previous
//
#include <hip/hip_runtime.h>
#include <hip/hip_bf16.h>

// GraphSAGE 3-layer, N=100000, E=1.6M, dims 256->256->128->1.
// R13: two changes vs R12.
// (1) prep_fused: degree-count+rank edges are interleaved INTO the x-convert
//     blocks (64 edges per block, 25000*64 = 1.6M) so the contended-atomic
//     latency chain overlaps the streaming conversion instead of running as
//     a serial tail phase (R12: 126us at 16% HBM, VALU 1%).
// (2) agg256_b / agg_gemv3: gather loop unrolled 4->8 (8 row loads in
//     flight, then 4-tail, then singles) to raise memory-level parallelism
//     (R12: agg256_b 127us at 3.7TB/s effective, latency-limited).

typedef __attribute__((ext_vector_type(8))) short short8;
typedef __attribute__((ext_vector_type(4))) float f32x4;

__device__ __forceinline__ unsigned short f2b(float f) {
    __hip_bfloat16 h = __float2bfloat16(f);
    return *reinterpret_cast<unsigned short*>(&h);
}
__device__ __forceinline__ float b2f(unsigned short u) {
    union { unsigned int i; float f; } v; v.i = ((unsigned int)u) << 16; return v.f;
}

// ---- fused prep: (convert_x + 64 edges) | prep_w x4 ----------------------
__global__ __launch_bounds__(256) void prep_fused(
    const float* __restrict__ x, unsigned short* __restrict__ xb,
    const float* __restrict__ Wl1, const float* __restrict__ Wr1,
    const float* __restrict__ Wl2, const float* __restrict__ Wr2,
    unsigned short* __restrict__ Wl1s, unsigned short* __restrict__ Wr1s,
    unsigned short* __restrict__ Wl2s, unsigned short* __restrict__ Wr2s,
    const int* __restrict__ dst, int* __restrict__ deg,
    unsigned short* __restrict__ rank, int E)
{
    const int b = blockIdx.x;
    const int tid = threadIdx.x;
    if (b < 25000) {
        // streaming convert: 1024 floats per block
        const int i = b * 256 + tid;
        float4 v = *(const float4*)(x + (size_t)i * 4);
        ushort4 o;
        o.x = f2b(v.x); o.y = f2b(v.y); o.z = f2b(v.z); o.w = f2b(v.w);
        *(ushort4*)(xb + (size_t)i * 4) = o;
        // interleaved degree-count: 64 edges per block (wave 0 only)
        if (tid < 64) {
            const int e = b * 64 + tid;
            if (e < E) rank[e] = (unsigned short)atomicAdd(&deg[dst[e]], 1);
        }
    } else {
        const float* W; unsigned short* O; int base, hs;
        if (b < 25256)      { W = Wl1; O = Wl1s; base = b - 25000; hs = 8; }
        else if (b < 25512) { W = Wr1; O = Wr1s; base = b - 25256; hs = 8; }
        else if (b < 25640) { W = Wl2; O = Wl2s; base = b - 25512; hs = 7; }
        else                { W = Wr2; O = Wr2s; base = b - 25640; hs = 7; }
        const int i = base * 256 + tid;
        const int k = i >> hs;
        const int h = i & ((1 << hs) - 1);
        O[((size_t)(((k >> 3) << hs) + h) << 3) + (k & 7)] = f2b(W[i]);
    }
}

// ---- scan ----------------------------------------------------------------
__global__ __launch_bounds__(256) void scan_phaseA(int* __restrict__ a,
                                                   int* __restrict__ blockSums, int n) {
    __shared__ int sh[256];
    const int tid = threadIdx.x;
    const int base = blockIdx.x * 1024 + tid * 4;
    int v[4];
    #pragma unroll
    for (int i = 0; i < 4; ++i) v[i] = (base + i < n) ? a[base + i] : 0;
    int tsum = v[0] + v[1] + v[2] + v[3];
    sh[tid] = tsum;
    __syncthreads();
    for (int off = 1; off < 256; off <<= 1) {
        int t = (tid >= off) ? sh[tid - off] : 0;
        __syncthreads();
        sh[tid] += t;
        __syncthreads();
    }
    int run = sh[tid] - tsum;
    #pragma unroll
    for (int i = 0; i < 4; ++i) {
        if (base + i < n) a[base + i] = run;
        run += v[i];
    }
    if (tid == 255) blockSums[blockIdx.x] = sh[255];
}

__global__ __launch_bounds__(256) void scan_phaseB(int* __restrict__ bs, int nb) {
    __shared__ int sh[256];
    const int tid = threadIdx.x;
    int v = (tid < nb) ? bs[tid] : 0;
    sh[tid] = v;
    __syncthreads();
    for (int off = 1; off < 256; off <<= 1) {
        int t = (tid >= off) ? sh[tid - off] : 0;
        __syncthreads();
        sh[tid] += t;
        __syncthreads();
    }
    if (tid < nb) bs[tid] = sh[tid] - v;
}

__global__ __launch_bounds__(256) void scan_phaseC(int* __restrict__ a,
                                                   const int* __restrict__ bs, int n) {
    const int base = blockIdx.x * 1024 + threadIdx.x * 4;
    const int add = bs[blockIdx.x];
    #pragma unroll
    for (int i = 0; i < 4; ++i)
        if (base + i < n) a[base + i] += add;
}

// ---- fused L1 GEMM (bf16 A) + atomic-free fill_csr -----------------------
__global__ __launch_bounds__(256) void gemm_l1_fill(
    const unsigned short* __restrict__ Xb,
    const unsigned short* __restrict__ Wsw_l,
    const unsigned short* __restrict__ Wsw_r,
    const float* __restrict__ bias,
    unsigned short* __restrict__ Tout,
    unsigned short* __restrict__ Abase,
    int M,
    const int* __restrict__ src, const int* __restrict__ dst,
    const int* __restrict__ starts, const unsigned short* __restrict__ rank,
    int* __restrict__ csr, int E)
{
    const int grp = blockIdx.x / 3;
    const int rem = blockIdx.x - grp * 3;
    const int tid = threadIdx.x;

    if (rem != 0) {                        // fill_csr part: no atomics
        const int e = (grp * 2 + rem - 1) * 256 + tid;
        if (e < E) csr[starts[dst[e]] + (int)rank[e]] = src[e];
        return;
    }

    // gemm part (H = 256)
    const int H = 256;
    const int wid = tid >> 6;
    const int lane = tid & 63;
    const int quad = lane >> 4;
    const int l15 = lane & 15;
    const int col0 = (grp & 3) << 6;
    const int m0 = (grp >> 2) * 128 + wid * 32;

    const unsigned short* aptr[2];
    #pragma unroll
    for (int mt = 0; mt < 2; ++mt) {
        int r = m0 + mt * 16 + l15;
        if (r > M - 1) r = M - 1;
        aptr[mt] = Xb + ((size_t)r << 8) + (quad << 3);
    }
    const unsigned short* bptr[8];   // 0..3 = Wl, 4..7 = Wr
    #pragma unroll
    for (int nt = 0; nt < 4; ++nt) {
        const int col = col0 + nt * 16 + l15;
        bptr[nt]     = Wsw_l + (((size_t)quad * H + col) << 3);
        bptr[nt + 4] = Wsw_r + (((size_t)quad * H + col) << 3);
    }

    const f32x4 zero = {0.f, 0.f, 0.f, 0.f};
    f32x4 acc[2][8];
    #pragma unroll
    for (int mt = 0; mt < 2; ++mt)
        #pragma unroll
        for (int nt = 0; nt < 8; ++nt) acc[mt][nt] = zero;

    #pragma unroll 2
    for (int ks = 0; ks < 8; ++ks) {
        short8 af[2], bf[8];
        #pragma unroll
        for (int mt = 0; mt < 2; ++mt)
            af[mt] = *(const short8*)(aptr[mt] + ks * 32);
        #pragma unroll
        for (int nt = 0; nt < 8; ++nt)
            bf[nt] = *(const short8*)(bptr[nt] + (size_t)ks * 32 * H);
        #pragma unroll
        for (int mt = 0; mt < 2; ++mt)
            #pragma unroll
            for (int nt = 0; nt < 8; ++nt)
                acc[mt][nt] = __builtin_amdgcn_mfma_f32_16x16x32_bf16(
                    af[mt], bf[nt], acc[mt][nt], 0, 0, 0);
    }

    #pragma unroll
    for (int nt = 0; nt < 4; ++nt) {
        const int colg = col0 + nt * 16 + l15;
        const float bb = bias[colg];
        #pragma unroll
        for (int mt = 0; mt < 2; ++mt) {
            const int gmb = m0 + mt * 16 + quad * 4;
            #pragma unroll
            for (int r = 0; r < 4; ++r) {
                if (gmb + r < M) {
                    Tout [(size_t)(gmb + r) * H + colg] = f2b(acc[mt][nt][r]);
                    Abase[(size_t)(gmb + r) * H + colg] = f2b(acc[mt][nt + 4][r] + bb);
                }
            }
        }
    }
}

// ---- layer-2 aggregation: half-wave per node, 16B/lane, 8-deep MLP -------
__global__ __launch_bounds__(256) void agg256_b(
    const int* __restrict__ endoff, const int* __restrict__ csr,
    const unsigned short* __restrict__ T,
    const unsigned short* __restrict__ Abase, unsigned short* __restrict__ Xout,
    int N, int E)
{
    const int node = (int)((blockIdx.x * 256 + threadIdx.x) >> 5);
    const int lane = threadIdx.x & 31;
    if (node >= N) return;
    const int beg = endoff[node];
    const int end = (node + 1 < N) ? endoff[node + 1] : E;
    float s[8] = {0.f, 0.f, 0.f, 0.f, 0.f, 0.f, 0.f, 0.f};
    int p = beg;
    for (; p + 8 <= end; p += 8) {
        int idx[8];
        #pragma unroll
        for (int u = 0; u < 8; ++u) idx[u] = csr[p + u];
        short8 v[8];
        #pragma unroll
        for (int u = 0; u < 8; ++u)
            v[u] = *(const short8*)(T + ((size_t)idx[u] << 8) + (lane << 3));
        #pragma unroll
        for (int j = 0; j < 8; ++j) {
            float t0 = b2f((unsigned short)v[0][j]) + b2f((unsigned short)v[1][j]);
            float t1 = b2f((unsigned short)v[2][j]) + b2f((unsigned short)v[3][j]);
            float t2 = b2f((unsigned short)v[4][j]) + b2f((unsigned short)v[5][j]);
            float t3 = b2f((unsigned short)v[6][j]) + b2f((unsigned short)v[7][j]);
            s[j] += (t0 + t1) + (t2 + t3);
        }
    }
    if (p + 4 <= end) {
        const int a = csr[p], b = csr[p + 1], c = csr[p + 2], d = csr[p + 3];
        const short8 v0 = *(const short8*)(T + ((size_t)a << 8) + (lane << 3));
        const short8 v1 = *(const short8*)(T + ((size_t)b << 8) + (lane << 3));
        const short8 v2 = *(const short8*)(T + ((size_t)c << 8) + (lane << 3));
        const short8 v3 = *(const short8*)(T + ((size_t)d << 8) + (lane << 3));
        #pragma unroll
        for (int j = 0; j < 8; ++j)
            s[j] += (b2f((unsigned short)v0[j]) + b2f((unsigned short)v1[j]))
                  + (b2f((unsigned short)v2[j]) + b2f((unsigned short)v3[j]));
        p += 4;
    }
    for (; p < end; ++p) {
        const short8 v = *(const short8*)(T + ((size_t)csr[p] << 8) + (lane << 3));
        #pragma unroll
        for (int j = 0; j < 8; ++j) s[j] += b2f((unsigned short)v[j]);
    }
    const float w = 1.0f / fmaxf((float)(end - beg), 1.0f);
    const short8 bu = *(const short8*)(Abase + ((size_t)node << 8) + (lane << 3));
    short8 o;
    #pragma unroll
    for (int j = 0; j < 8; ++j)
        o[j] = (short)f2b(fmaxf(b2f((unsigned short)bu[j]) + s[j] * w, 0.f));
    *(short8*)(Xout + ((size_t)node << 8) + (lane << 3)) = o;
}

// ---- standalone L2 GEMM (H=128, K=256) -----------------------------------
__global__ __launch_bounds__(256) void gemm_bf16(
    const unsigned short* __restrict__ Xb,
    const unsigned short* __restrict__ Wsw_l,
    const unsigned short* __restrict__ Wsw_r,
    const float* __restrict__ bias,
    unsigned short* __restrict__ Tout,
    unsigned short* __restrict__ Abase,
    int M, int H)
{
    const int tid = threadIdx.x;
    const int wid = tid >> 6;
    const int lane = tid & 63;
    const int quad = lane >> 4;
    const int l15 = lane & 15;

    const int col0 = blockIdx.x << 6;
    const int m0 = blockIdx.y * 128 + wid * 32;

    const unsigned short* aptr[2];
    #pragma unroll
    for (int mt = 0; mt < 2; ++mt) {
        int r = m0 + mt * 16 + l15;
        if (r > M - 1) r = M - 1;
        aptr[mt] = Xb + ((size_t)r << 8) + (quad << 3);
    }
    const unsigned short* bptr[8];
    #pragma unroll
    for (int nt = 0; nt < 4; ++nt) {
        const int col = col0 + nt * 16 + l15;
        bptr[nt]     = Wsw_l + (((size_t)quad * H + col) << 3);
        bptr[nt + 4] = Wsw_r + (((size_t)quad * H + col) << 3);
    }

    const f32x4 zero = {0.f, 0.f, 0.f, 0.f};
    f32x4 acc[2][8];
    #pragma unroll
    for (int mt = 0; mt < 2; ++mt)
        #pragma unroll
        for (int nt = 0; nt < 8; ++nt) acc[mt][nt] = zero;

    #pragma unroll 2
    for (int ks = 0; ks < 8; ++ks) {
        short8 af[2], bf[8];
        #pragma unroll
        for (int mt = 0; mt < 2; ++mt)
            af[mt] = *(const short8*)(aptr[mt] + ks * 32);
        #pragma unroll
        for (int nt = 0; nt < 8; ++nt)
            bf[nt] = *(const short8*)(bptr[nt] + (size_t)ks * 32 * H);
        #pragma unroll
        for (int mt = 0; mt < 2; ++mt)
            #pragma unroll
            for (int nt = 0; nt < 8; ++nt)
                acc[mt][nt] = __builtin_amdgcn_mfma_f32_16x16x32_bf16(
                    af[mt], bf[nt], acc[mt][nt], 0, 0, 0);
    }

    #pragma unroll
    for (int nt = 0; nt < 4; ++nt) {
        const int colg = col0 + nt * 16 + l15;
        const float bb = bias[colg];
        #pragma unroll
        for (int mt = 0; mt < 2; ++mt) {
            const int gmb = m0 + mt * 16 + quad * 4;
            #pragma unroll
            for (int r = 0; r < 4; ++r) {
                if (gmb + r < M) {
                    Tout [(size_t)(gmb + r) * H + colg] = f2b(acc[mt][nt][r]);
                    Abase[(size_t)(gmb + r) * H + colg] = f2b(acc[mt][nt + 4][r] + bb);
                }
            }
        }
    }
}

// ---- fused layer-3: agg128 + gemv, 8-deep MLP ----------------------------
__global__ __launch_bounds__(256) void agg_gemv3(
    const int* __restrict__ endoff, const int* __restrict__ csr,
    const unsigned short* __restrict__ T, const unsigned short* __restrict__ Ab,
    const float* __restrict__ Wl, const float* __restrict__ Wr,
    const float* __restrict__ b,
    float* __restrict__ t3, float* __restrict__ out, int N, int E)
{
    const int node = (int)((blockIdx.x * 256 + threadIdx.x) >> 5);
    const int lane = threadIdx.x & 31;
    if (node >= N) return;
    const int beg = endoff[node];
    const int end = (node + 1 < N) ? endoff[node + 1] : E;
    float s0 = 0.f, s1 = 0.f, s2 = 0.f, s3 = 0.f;
    int p = beg;
    for (; p + 8 <= end; p += 8) {
        int idx[8];
        #pragma unroll
        for (int u = 0; u < 8; ++u) idx[u] = csr[p + u];
        ushort4 v[8];
        #pragma unroll
        for (int u = 0; u < 8; ++u)
            v[u] = *(const ushort4*)(T + ((size_t)idx[u] << 7) + (lane << 2));
        #pragma unroll
        for (int u = 0; u < 8; ++u) {
            s0 += b2f(v[u].x); s1 += b2f(v[u].y);
            s2 += b2f(v[u].z); s3 += b2f(v[u].w);
        }
    }
    if (p + 4 <= end) {
        const int a = csr[p], bb = csr[p + 1], c = csr[p + 2], d = csr[p + 3];
        ushort4 v0 = *(const ushort4*)(T + ((size_t)a << 7) + (lane << 2));
        ushort4 v1 = *(const ushort4*)(T + ((size_t)bb << 7) + (lane << 2));
        ushort4 v2 = *(const ushort4*)(T + ((size_t)c << 7) + (lane << 2));
        ushort4 v3 = *(const ushort4*)(T + ((size_t)d << 7) + (lane << 2));
        s0 += (b2f(v0.x) + b2f(v1.x)) + (b2f(v2.x) + b2f(v3.x));
        s1 += (b2f(v0.y) + b2f(v1.y)) + (b2f(v2.y) + b2f(v3.y));
        s2 += (b2f(v0.z) + b2f(v1.z)) + (b2f(v2.z) + b2f(v3.z));
        s3 += (b2f(v0.w) + b2f(v1.w)) + (b2f(v2.w) + b2f(v3.w));
        p += 4;
    }
    for (; p < end; ++p) {
        ushort4 v = *(const ushort4*)(T + ((size_t)csr[p] << 7) + (lane << 2));
        s0 += b2f(v.x); s1 += b2f(v.y); s2 += b2f(v.z); s3 += b2f(v.w);
    }
    const float w = 1.0f / fmaxf((float)(end - beg), 1.0f);
    const ushort4 bu = *(const ushort4*)(Ab + ((size_t)node << 7) + (lane << 2));
    const float h0 = fmaxf(b2f(bu.x) + s0 * w, 0.f);
    const float h1 = fmaxf(b2f(bu.y) + s1 * w, 0.f);
    const float h2 = fmaxf(b2f(bu.z) + s2 * w, 0.f);
    const float h3 = fmaxf(b2f(bu.w) + s3 * w, 0.f);

    const float4 wl = *(const float4*)(Wl + (lane << 2));
    const float4 wr = *(const float4*)(Wr + (lane << 2));
    float dl = h0 * wl.x + h1 * wl.y + h2 * wl.z + h3 * wl.w;
    float dr = h0 * wr.x + h1 * wr.y + h2 * wr.z + h3 * wr.w;
    #pragma unroll
    for (int off = 16; off > 0; off >>= 1) {
        dl += __shfl_down(dl, off, 64);
        dr += __shfl_down(dr, off, 64);
    }
    if (lane == 0) {
        t3[node] = dl;
        out[node] = dr + b[0];
    }
}

__global__ __launch_bounds__(256) void agg1(
    const int* __restrict__ endoff, const int* __restrict__ csr,
    const float* __restrict__ t3, float* __restrict__ out, int N, int E)
{
    const int i = blockIdx.x * blockDim.x + threadIdx.x;
    if (i >= N) return;
    const int beg = endoff[i];
    const int end = (i + 1 < N) ? endoff[i + 1] : E;
    int p = beg;
    float s = 0.f;
    for (; p + 4 <= end; p += 4)
        s += (t3[csr[p]] + t3[csr[p + 1]]) + (t3[csr[p + 2]] + t3[csr[p + 3]]);
    for (; p < end; ++p) s += t3[csr[p]];
    out[i] += s / fmaxf((float)(end - beg), 1.0f);
}

extern "C" void kernel_launch(void* const* d_in, const int* in_sizes, int n_in,
                              void* d_out, int out_size, void* d_ws, size_t ws_size,
                              hipStream_t stream) {
    const float* x   = (const float*)d_in[0];
    const int*   ei  = (const int*)d_in[1];
    const float* Wl1 = (const float*)d_in[2];
    const float* bl1 = (const float*)d_in[3];
    const float* Wr1 = (const float*)d_in[4];
    const float* Wl2 = (const float*)d_in[5];
    const float* bl2 = (const float*)d_in[6];
    const float* Wr2 = (const float*)d_in[7];
    const float* Wl3 = (const float*)d_in[8];
    const float* bl3 = (const float*)d_in[9];
    const float* Wr3 = (const float*)d_in[10];
    float* out = (float*)d_out;

    const int N = in_sizes[0] / 256;   // 100000
    const int E = in_sizes[1] / 2;     // 1600000
    const int* src = ei;
    const int* dst = ei + E;

    // ---- workspace layout, race-free aliasing ----------------------------
    char* W = (char*)d_ws;
    const size_t MB512 = (size_t)100000 * 512;   // 51.2MB
    unsigned short* X1b = (unsigned short*)(W);
    unsigned short* T1b = (unsigned short*)(W + MB512);
    unsigned short* A1b = (unsigned short*)(W + 2 * MB512);
    unsigned short* X2b = (unsigned short*)(W);                  // over dead X1b
    unsigned short* T2b = (unsigned short*)(W + MB512);          // over dead T1b
    unsigned short* A2b = (unsigned short*)(W + MB512 + MB512 / 2);
    char* S = W + 3 * MB512;                     // smalls @ 153.6M
    int*   endoff = (int*)(S);
    int*   bsums  = (int*)(S + (size_t)N * 4);
    float* t3     = (float*)(S + (size_t)N * 4 + 1024);
    int*   csr    = (int*)(S + (size_t)N * 8 + 1024);
    unsigned short* Wl1s = (unsigned short*)(S + (size_t)N * 8 + 1024 + (size_t)E * 4);
    unsigned short* Wr1s = Wl1s + 65536;
    unsigned short* Wl2s = Wr1s + 65536;
    unsigned short* Wr2s = Wl2s + 32768;
    unsigned short* rank = Wr2s + 32768;         // ushort[E], +3.2MB

    // ---- prep: fused conversions + interleaved degree count ----
    hipMemsetAsync(endoff, 0, (size_t)N * sizeof(int), stream);
    prep_fused<<<25768, 256, 0, stream>>>(
        x, X1b, Wl1, Wr1, Wl2, Wr2, Wl1s, Wr1s, Wl2s, Wr2s,
        dst, endoff, rank, E);
    const int nScanBlocks = (N + 1023) / 1024;
    scan_phaseA<<<nScanBlocks, 256, 0, stream>>>(endoff, bsums, N);
    scan_phaseB<<<1, 256, 0, stream>>>(bsums, nScanBlocks);
    scan_phaseC<<<nScanBlocks, 256, 0, stream>>>(endoff, bsums, N);

    // ---- Layer 1 GEMM (bf16 A) fused with atomic-free fill_csr ----
    gemm_l1_fill<<<3128 * 3, 256, 0, stream>>>(X1b, Wl1s, Wr1s, bl1, T1b, A1b, N,
                                               src, dst, endoff, rank, csr, E);

    // ---- Layer 2: gather (half-wave/node) then GEMM ----
    agg256_b<<<(N * 32 + 255) / 256, 256, 0, stream>>>(endoff, csr, T1b, A1b, X2b, N, E);
    gemm_bf16<<<dim3(2, (N + 127) / 128), 256, 0, stream>>>(X2b, Wl2s, Wr2s, bl2,
                                                            T2b, A2b, N, 128);

    // ---- Layer 3: fused agg128 + gemv, then final scalar aggregation ----
    agg_gemv3<<<(N * 32 + 255) / 256, 256, 0, stream>>>(endoff, csr, T2b, A2b,
                                                        Wl3, Wr3, bl3, t3, out, N, E);
    agg1<<<(N + 255) / 256, 256, 0, stream>>>(endoff, csr, t3, out, N, E);
}

// Round 4
// 545.749 us; speedup vs baseline: 1.1321x; 1.0446x over previous
//
#include <hip/hip_runtime.h>
#include <hip/hip_bf16.h>

// GraphSAGE 3-layer, N=100000, E=1.6M, dims 256->256->128->1.
// R14: gemm_l1_fill's GEMM branch rebuilt as an LDS-staged K-loop
// (m97-lite): per K-stage (BK=64) stage A(128x64, 16KB) + B(64x128 fused,
// 16KB) via global_load_lds width=16, single-buffered with 2 barriers.
// A content-swizzled on the GLOBAL source (chunk ^= row&7) so fragment
// ds_read_b128 sits at the bank floor. Bijective XCD swizzle over the
// 9384-block grid (8*1173) so a row-panel's 4 column-blocks share one
// XCD L2. Fill path and all other kernels unchanged from R13.

typedef __attribute__((ext_vector_type(8))) short short8;
typedef __attribute__((ext_vector_type(4))) float f32x4;

__device__ __forceinline__ unsigned short f2b(float f) {
    __hip_bfloat16 h = __float2bfloat16(f);
    return *reinterpret_cast<unsigned short*>(&h);
}
__device__ __forceinline__ float b2f(unsigned short u) {
    union { unsigned int i; float f; } v; v.i = ((unsigned int)u) << 16; return v.f;
}

__device__ __forceinline__ void gload_lds16(const unsigned short* g, unsigned short* l) {
    __builtin_amdgcn_global_load_lds(
        (const __attribute__((address_space(1))) unsigned int*)(const void*)g,
        (__attribute__((address_space(3))) unsigned int*)(void*)l,
        16, 0, 0);
}

// ---- fused prep: (convert_x + 64 edges) | prep_w x4 ----------------------
__global__ __launch_bounds__(256) void prep_fused(
    const float* __restrict__ x, unsigned short* __restrict__ xb,
    const float* __restrict__ Wl1, const float* __restrict__ Wr1,
    const float* __restrict__ Wl2, const float* __restrict__ Wr2,
    unsigned short* __restrict__ Wl1s, unsigned short* __restrict__ Wr1s,
    unsigned short* __restrict__ Wl2s, unsigned short* __restrict__ Wr2s,
    const int* __restrict__ dst, int* __restrict__ deg,
    unsigned short* __restrict__ rank, int E)
{
    const int b = blockIdx.x;
    const int tid = threadIdx.x;
    if (b < 25000) {
        const int i = b * 256 + tid;
        float4 v = *(const float4*)(x + (size_t)i * 4);
        ushort4 o;
        o.x = f2b(v.x); o.y = f2b(v.y); o.z = f2b(v.z); o.w = f2b(v.w);
        *(ushort4*)(xb + (size_t)i * 4) = o;
        if (tid < 64) {
            const int e = b * 64 + tid;
            if (e < E) rank[e] = (unsigned short)atomicAdd(&deg[dst[e]], 1);
        }
    } else {
        const float* W; unsigned short* O; int base, hs;
        if (b < 25256)      { W = Wl1; O = Wl1s; base = b - 25000; hs = 8; }
        else if (b < 25512) { W = Wr1; O = Wr1s; base = b - 25256; hs = 8; }
        else if (b < 25640) { W = Wl2; O = Wl2s; base = b - 25512; hs = 7; }
        else                { W = Wr2; O = Wr2s; base = b - 25640; hs = 7; }
        const int i = base * 256 + tid;
        const int k = i >> hs;
        const int h = i & ((1 << hs) - 1);
        O[((size_t)(((k >> 3) << hs) + h) << 3) + (k & 7)] = f2b(W[i]);
    }
}

// ---- scan ----------------------------------------------------------------
__global__ __launch_bounds__(256) void scan_phaseA(int* __restrict__ a,
                                                   int* __restrict__ blockSums, int n) {
    __shared__ int sh[256];
    const int tid = threadIdx.x;
    const int base = blockIdx.x * 1024 + tid * 4;
    int v[4];
    #pragma unroll
    for (int i = 0; i < 4; ++i) v[i] = (base + i < n) ? a[base + i] : 0;
    int tsum = v[0] + v[1] + v[2] + v[3];
    sh[tid] = tsum;
    __syncthreads();
    for (int off = 1; off < 256; off <<= 1) {
        int t = (tid >= off) ? sh[tid - off] : 0;
        __syncthreads();
        sh[tid] += t;
        __syncthreads();
    }
    int run = sh[tid] - tsum;
    #pragma unroll
    for (int i = 0; i < 4; ++i) {
        if (base + i < n) a[base + i] = run;
        run += v[i];
    }
    if (tid == 255) blockSums[blockIdx.x] = sh[255];
}

__global__ __launch_bounds__(256) void scan_phaseB(int* __restrict__ bs, int nb) {
    __shared__ int sh[256];
    const int tid = threadIdx.x;
    int v = (tid < nb) ? bs[tid] : 0;
    sh[tid] = v;
    __syncthreads();
    for (int off = 1; off < 256; off <<= 1) {
        int t = (tid >= off) ? sh[tid - off] : 0;
        __syncthreads();
        sh[tid] += t;
        __syncthreads();
    }
    if (tid < nb) bs[tid] = sh[tid] - v;
}

__global__ __launch_bounds__(256) void scan_phaseC(int* __restrict__ a,
                                                   const int* __restrict__ bs, int n) {
    const int base = blockIdx.x * 1024 + threadIdx.x * 4;
    const int add = bs[blockIdx.x];
    #pragma unroll
    for (int i = 0; i < 4; ++i)
        if (base + i < n) a[base + i] += add;
}

// ---- fused L1 GEMM (LDS-staged) + atomic-free fill_csr -------------------
__global__ __launch_bounds__(256) void gemm_l1_fill(
    const unsigned short* __restrict__ Xb,
    const unsigned short* __restrict__ Wsw_l,
    const unsigned short* __restrict__ Wsw_r,
    const float* __restrict__ bias,
    unsigned short* __restrict__ Tout,
    unsigned short* __restrict__ Abase,
    int M,
    const int* __restrict__ src, const int* __restrict__ dst,
    const int* __restrict__ starts, const unsigned short* __restrict__ rank,
    int* __restrict__ csr, int E)
{
    // bijective XCD swizzle: grid = 9384 = 8 * 1173
    const int bid = (blockIdx.x & 7) * 1173 + (blockIdx.x >> 3);
    const int grp = bid / 3;
    const int rem = bid - grp * 3;
    const int tid = threadIdx.x;

    if (rem != 0) {                        // fill_csr part: no atomics
        const int e = (grp * 2 + rem - 1) * 256 + tid;
        if (e < E) csr[starts[dst[e]] + (int)rank[e]] = src[e];
        return;
    }

    // ---- gemm part: 128 rows x 64 cols x {Wl,Wr}, K=256, BK=64 ----------
    // LDS: A [row 128][chunk 8] x16B = 16KB at smem[0]
    //      B [mat 2][ko 8][col 64] x16B = 16KB at smem[8192] (ushort units)
    __shared__ unsigned short smem[16384];

    const int wid = tid >> 6;
    const int lane = tid & 63;
    const int quad = lane >> 4;
    const int l15 = lane & 15;
    const int col0 = (grp & 3) << 6;
    const int m0 = (grp >> 2) * 128;

    // staging descriptors (4 A-issues + 4 B-issues of 4KB each)
    const unsigned short* aSrc[4];
    unsigned int aOfs[4];                  // ushort offsets in smem
    #pragma unroll
    for (int i = 0; i < 4; ++i) {
        const int slot = i * 256 + tid;
        const int r = slot >> 3, cs = slot & 7;
        const int cg = cs ^ (r & 7);       // content swizzle on global source
        aSrc[i] = Xb + ((size_t)(m0 + r) << 8) + (cg << 3);
        aOfs[i] = (unsigned)((i * 256 + wid * 64) * 8);
    }
    const unsigned short* bSrc[4];
    unsigned int bOfs[4];
    #pragma unroll
    for (int i = 0; i < 4; ++i) {
        const int slot = i * 256 + tid;
        const int mat = slot >> 9, ko = (slot >> 6) & 7, col = slot & 63;
        const unsigned short* Wm = mat ? Wsw_r : Wsw_l;
        bSrc[i] = Wm + (((size_t)ko * 256 + col0 + col) << 3);
        bOfs[i] = (unsigned)(8192 + (i * 256 + wid * 64) * 8);
    }

    const f32x4 zero = {0.f, 0.f, 0.f, 0.f};
    f32x4 acc[2][8];
    #pragma unroll
    for (int mt = 0; mt < 2; ++mt)
        #pragma unroll
        for (int nt = 0; nt < 8; ++nt) acc[mt][nt] = zero;

    for (int ks = 0; ks < 4; ++ks) {
        #pragma unroll
        for (int i = 0; i < 4; ++i)
            gload_lds16(aSrc[i] + ks * 64, smem + aOfs[i]);
        #pragma unroll
        for (int i = 0; i < 4; ++i)
            gload_lds16(bSrc[i] + ks * 16384, smem + bOfs[i]);
        __syncthreads();                   // drains vmcnt -> LDS valid

        #pragma unroll
        for (int k32 = 0; k32 < 2; ++k32) {
            short8 af[2], bf[8];
            #pragma unroll
            for (int mt = 0; mt < 2; ++mt) {
                const int row = wid * 32 + mt * 16 + l15;
                const int c = (k32 * 4 + quad) ^ (row & 7);
                af[mt] = *(const short8*)(smem + ((row << 3) + c) * 8);
            }
            #pragma unroll
            for (int nt = 0; nt < 4; ++nt) {
                const int colL = nt * 16 + l15;
                const int ko = k32 * 4 + quad;
                bf[nt]     = *(const short8*)(smem + 8192 + ((ko << 6) + colL) * 8);
                bf[nt + 4] = *(const short8*)(smem + 8192 + (512 + (ko << 6) + colL) * 8);
            }
            #pragma unroll
            for (int mt = 0; mt < 2; ++mt)
                #pragma unroll
                for (int nt = 0; nt < 8; ++nt)
                    acc[mt][nt] = __builtin_amdgcn_mfma_f32_16x16x32_bf16(
                        af[mt], bf[nt], acc[mt][nt], 0, 0, 0);
        }
        __syncthreads();
    }

    #pragma unroll
    for (int nt = 0; nt < 4; ++nt) {
        const int colg = col0 + nt * 16 + l15;
        const float bb = bias[colg];
        #pragma unroll
        for (int mt = 0; mt < 2; ++mt) {
            const int gmb = m0 + wid * 32 + mt * 16 + quad * 4;
            #pragma unroll
            for (int r = 0; r < 4; ++r) {
                if (gmb + r < M) {
                    Tout [(size_t)(gmb + r) * 256 + colg] = f2b(acc[mt][nt][r]);
                    Abase[(size_t)(gmb + r) * 256 + colg] = f2b(acc[mt][nt + 4][r] + bb);
                }
            }
        }
    }
}

// ---- layer-2 aggregation: half-wave per node, 16B/lane, 8-deep MLP -------
__global__ __launch_bounds__(256) void agg256_b(
    const int* __restrict__ endoff, const int* __restrict__ csr,
    const unsigned short* __restrict__ T,
    const unsigned short* __restrict__ Abase, unsigned short* __restrict__ Xout,
    int N, int E)
{
    const int node = (int)((blockIdx.x * 256 + threadIdx.x) >> 5);
    const int lane = threadIdx.x & 31;
    if (node >= N) return;
    const int beg = endoff[node];
    const int end = (node + 1 < N) ? endoff[node + 1] : E;
    float s[8] = {0.f, 0.f, 0.f, 0.f, 0.f, 0.f, 0.f, 0.f};
    int p = beg;
    for (; p + 8 <= end; p += 8) {
        int idx[8];
        #pragma unroll
        for (int u = 0; u < 8; ++u) idx[u] = csr[p + u];
        short8 v[8];
        #pragma unroll
        for (int u = 0; u < 8; ++u)
            v[u] = *(const short8*)(T + ((size_t)idx[u] << 8) + (lane << 3));
        #pragma unroll
        for (int j = 0; j < 8; ++j) {
            float t0 = b2f((unsigned short)v[0][j]) + b2f((unsigned short)v[1][j]);
            float t1 = b2f((unsigned short)v[2][j]) + b2f((unsigned short)v[3][j]);
            float t2 = b2f((unsigned short)v[4][j]) + b2f((unsigned short)v[5][j]);
            float t3 = b2f((unsigned short)v[6][j]) + b2f((unsigned short)v[7][j]);
            s[j] += (t0 + t1) + (t2 + t3);
        }
    }
    if (p + 4 <= end) {
        const int a = csr[p], b = csr[p + 1], c = csr[p + 2], d = csr[p + 3];
        const short8 v0 = *(const short8*)(T + ((size_t)a << 8) + (lane << 3));
        const short8 v1 = *(const short8*)(T + ((size_t)b << 8) + (lane << 3));
        const short8 v2 = *(const short8*)(T + ((size_t)c << 8) + (lane << 3));
        const short8 v3 = *(const short8*)(T + ((size_t)d << 8) + (lane << 3));
        #pragma unroll
        for (int j = 0; j < 8; ++j)
            s[j] += (b2f((unsigned short)v0[j]) + b2f((unsigned short)v1[j]))
                  + (b2f((unsigned short)v2[j]) + b2f((unsigned short)v3[j]));
        p += 4;
    }
    for (; p < end; ++p) {
        const short8 v = *(const short8*)(T + ((size_t)csr[p] << 8) + (lane << 3));
        #pragma unroll
        for (int j = 0; j < 8; ++j) s[j] += b2f((unsigned short)v[j]);
    }
    const float w = 1.0f / fmaxf((float)(end - beg), 1.0f);
    const short8 bu = *(const short8*)(Abase + ((size_t)node << 8) + (lane << 3));
    short8 o;
    #pragma unroll
    for (int j = 0; j < 8; ++j)
        o[j] = (short)f2b(fmaxf(b2f((unsigned short)bu[j]) + s[j] * w, 0.f));
    *(short8*)(Xout + ((size_t)node << 8) + (lane << 3)) = o;
}

// ---- standalone L2 GEMM (H=128, K=256) -----------------------------------
__global__ __launch_bounds__(256) void gemm_bf16(
    const unsigned short* __restrict__ Xb,
    const unsigned short* __restrict__ Wsw_l,
    const unsigned short* __restrict__ Wsw_r,
    const float* __restrict__ bias,
    unsigned short* __restrict__ Tout,
    unsigned short* __restrict__ Abase,
    int M, int H)
{
    const int tid = threadIdx.x;
    const int wid = tid >> 6;
    const int lane = tid & 63;
    const int quad = lane >> 4;
    const int l15 = lane & 15;

    const int col0 = blockIdx.x << 6;
    const int m0 = blockIdx.y * 128 + wid * 32;

    const unsigned short* aptr[2];
    #pragma unroll
    for (int mt = 0; mt < 2; ++mt) {
        int r = m0 + mt * 16 + l15;
        if (r > M - 1) r = M - 1;
        aptr[mt] = Xb + ((size_t)r << 8) + (quad << 3);
    }
    const unsigned short* bptr[8];
    #pragma unroll
    for (int nt = 0; nt < 4; ++nt) {
        const int col = col0 + nt * 16 + l15;
        bptr[nt]     = Wsw_l + (((size_t)quad * H + col) << 3);
        bptr[nt + 4] = Wsw_r + (((size_t)quad * H + col) << 3);
    }

    const f32x4 zero = {0.f, 0.f, 0.f, 0.f};
    f32x4 acc[2][8];
    #pragma unroll
    for (int mt = 0; mt < 2; ++mt)
        #pragma unroll
        for (int nt = 0; nt < 8; ++nt) acc[mt][nt] = zero;

    #pragma unroll 2
    for (int ks = 0; ks < 8; ++ks) {
        short8 af[2], bf[8];
        #pragma unroll
        for (int mt = 0; mt < 2; ++mt)
            af[mt] = *(const short8*)(aptr[mt] + ks * 32);
        #pragma unroll
        for (int nt = 0; nt < 8; ++nt)
            bf[nt] = *(const short8*)(bptr[nt] + (size_t)ks * 32 * H);
        #pragma unroll
        for (int mt = 0; mt < 2; ++mt)
            #pragma unroll
            for (int nt = 0; nt < 8; ++nt)
                acc[mt][nt] = __builtin_amdgcn_mfma_f32_16x16x32_bf16(
                    af[mt], bf[nt], acc[mt][nt], 0, 0, 0);
    }

    #pragma unroll
    for (int nt = 0; nt < 4; ++nt) {
        const int colg = col0 + nt * 16 + l15;
        const float bb = bias[colg];
        #pragma unroll
        for (int mt = 0; mt < 2; ++mt) {
            const int gmb = m0 + mt * 16 + quad * 4;
            #pragma unroll
            for (int r = 0; r < 4; ++r) {
                if (gmb + r < M) {
                    Tout [(size_t)(gmb + r) * H + colg] = f2b(acc[mt][nt][r]);
                    Abase[(size_t)(gmb + r) * H + colg] = f2b(acc[mt][nt + 4][r] + bb);
                }
            }
        }
    }
}

// ---- fused layer-3: agg128 + gemv, 8-deep MLP ----------------------------
__global__ __launch_bounds__(256) void agg_gemv3(
    const int* __restrict__ endoff, const int* __restrict__ csr,
    const unsigned short* __restrict__ T, const unsigned short* __restrict__ Ab,
    const float* __restrict__ Wl, const float* __restrict__ Wr,
    const float* __restrict__ b,
    float* __restrict__ t3, float* __restrict__ out, int N, int E)
{
    const int node = (int)((blockIdx.x * 256 + threadIdx.x) >> 5);
    const int lane = threadIdx.x & 31;
    if (node >= N) return;
    const int beg = endoff[node];
    const int end = (node + 1 < N) ? endoff[node + 1] : E;
    float s0 = 0.f, s1 = 0.f, s2 = 0.f, s3 = 0.f;
    int p = beg;
    for (; p + 8 <= end; p += 8) {
        int idx[8];
        #pragma unroll
        for (int u = 0; u < 8; ++u) idx[u] = csr[p + u];
        ushort4 v[8];
        #pragma unroll
        for (int u = 0; u < 8; ++u)
            v[u] = *(const ushort4*)(T + ((size_t)idx[u] << 7) + (lane << 2));
        #pragma unroll
        for (int u = 0; u < 8; ++u) {
            s0 += b2f(v[u].x); s1 += b2f(v[u].y);
            s2 += b2f(v[u].z); s3 += b2f(v[u].w);
        }
    }
    if (p + 4 <= end) {
        const int a = csr[p], bb = csr[p + 1], c = csr[p + 2], d = csr[p + 3];
        ushort4 v0 = *(const ushort4*)(T + ((size_t)a << 7) + (lane << 2));
        ushort4 v1 = *(const ushort4*)(T + ((size_t)bb << 7) + (lane << 2));
        ushort4 v2 = *(const ushort4*)(T + ((size_t)c << 7) + (lane << 2));
        ushort4 v3 = *(const ushort4*)(T + ((size_t)d << 7) + (lane << 2));
        s0 += (b2f(v0.x) + b2f(v1.x)) + (b2f(v2.x) + b2f(v3.x));
        s1 += (b2f(v0.y) + b2f(v1.y)) + (b2f(v2.y) + b2f(v3.y));
        s2 += (b2f(v0.z) + b2f(v1.z)) + (b2f(v2.z) + b2f(v3.z));
        s3 += (b2f(v0.w) + b2f(v1.w)) + (b2f(v2.w) + b2f(v3.w));
        p += 4;
    }
    for (; p < end; ++p) {
        ushort4 v = *(const ushort4*)(T + ((size_t)csr[p] << 7) + (lane << 2));
        s0 += b2f(v.x); s1 += b2f(v.y); s2 += b2f(v.z); s3 += b2f(v.w);
    }
    const float w = 1.0f / fmaxf((float)(end - beg), 1.0f);
    const ushort4 bu = *(const ushort4*)(Ab + ((size_t)node << 7) + (lane << 2));
    const float h0 = fmaxf(b2f(bu.x) + s0 * w, 0.f);
    const float h1 = fmaxf(b2f(bu.y) + s1 * w, 0.f);
    const float h2 = fmaxf(b2f(bu.z) + s2 * w, 0.f);
    const float h3 = fmaxf(b2f(bu.w) + s3 * w, 0.f);

    const float4 wl = *(const float4*)(Wl + (lane << 2));
    const float4 wr = *(const float4*)(Wr + (lane << 2));
    float dl = h0 * wl.x + h1 * wl.y + h2 * wl.z + h3 * wl.w;
    float dr = h0 * wr.x + h1 * wr.y + h2 * wr.z + h3 * wr.w;
    #pragma unroll
    for (int off = 16; off > 0; off >>= 1) {
        dl += __shfl_down(dl, off, 64);
        dr += __shfl_down(dr, off, 64);
    }
    if (lane == 0) {
        t3[node] = dl;
        out[node] = dr + b[0];
    }
}

__global__ __launch_bounds__(256) void agg1(
    const int* __restrict__ endoff, const int* __restrict__ csr,
    const float* __restrict__ t3, float* __restrict__ out, int N, int E)
{
    const int i = blockIdx.x * blockDim.x + threadIdx.x;
    if (i >= N) return;
    const int beg = endoff[i];
    const int end = (i + 1 < N) ? endoff[i + 1] : E;
    int p = beg;
    float s = 0.f;
    for (; p + 4 <= end; p += 4)
        s += (t3[csr[p]] + t3[csr[p + 1]]) + (t3[csr[p + 2]] + t3[csr[p + 3]]);
    for (; p < end; ++p) s += t3[csr[p]];
    out[i] += s / fmaxf((float)(end - beg), 1.0f);
}

extern "C" void kernel_launch(void* const* d_in, const int* in_sizes, int n_in,
                              void* d_out, int out_size, void* d_ws, size_t ws_size,
                              hipStream_t stream) {
    const float* x   = (const float*)d_in[0];
    const int*   ei  = (const int*)d_in[1];
    const float* Wl1 = (const float*)d_in[2];
    const float* bl1 = (const float*)d_in[3];
    const float* Wr1 = (const float*)d_in[4];
    const float* Wl2 = (const float*)d_in[5];
    const float* bl2 = (const float*)d_in[6];
    const float* Wr2 = (const float*)d_in[7];
    const float* Wl3 = (const float*)d_in[8];
    const float* bl3 = (const float*)d_in[9];
    const float* Wr3 = (const float*)d_in[10];
    float* out = (float*)d_out;

    const int N = in_sizes[0] / 256;   // 100000
    const int E = in_sizes[1] / 2;     // 1600000
    const int* src = ei;
    const int* dst = ei + E;

    // ---- workspace layout, race-free aliasing ----------------------------
    char* W = (char*)d_ws;
    const size_t MB512 = (size_t)100000 * 512;   // 51.2MB
    unsigned short* X1b = (unsigned short*)(W);
    unsigned short* T1b = (unsigned short*)(W + MB512);
    unsigned short* A1b = (unsigned short*)(W + 2 * MB512);
    unsigned short* X2b = (unsigned short*)(W);                  // over dead X1b
    unsigned short* T2b = (unsigned short*)(W + MB512);          // over dead T1b
    unsigned short* A2b = (unsigned short*)(W + MB512 + MB512 / 2);
    char* S = W + 3 * MB512;                     // smalls @ 153.6M
    int*   endoff = (int*)(S);
    int*   bsums  = (int*)(S + (size_t)N * 4);
    float* t3     = (float*)(S + (size_t)N * 4 + 1024);
    int*   csr    = (int*)(S + (size_t)N * 8 + 1024);
    unsigned short* Wl1s = (unsigned short*)(S + (size_t)N * 8 + 1024 + (size_t)E * 4);
    unsigned short* Wr1s = Wl1s + 65536;
    unsigned short* Wl2s = Wr1s + 65536;
    unsigned short* Wr2s = Wl2s + 32768;
    unsigned short* rank = Wr2s + 32768;         // ushort[E], +3.2MB

    // ---- prep: fused conversions + interleaved degree count ----
    hipMemsetAsync(endoff, 0, (size_t)N * sizeof(int), stream);
    prep_fused<<<25768, 256, 0, stream>>>(
        x, X1b, Wl1, Wr1, Wl2, Wr2, Wl1s, Wr1s, Wl2s, Wr2s,
        dst, endoff, rank, E);
    const int nScanBlocks = (N + 1023) / 1024;
    scan_phaseA<<<nScanBlocks, 256, 0, stream>>>(endoff, bsums, N);
    scan_phaseB<<<1, 256, 0, stream>>>(bsums, nScanBlocks);
    scan_phaseC<<<nScanBlocks, 256, 0, stream>>>(endoff, bsums, N);

    // ---- Layer 1 GEMM (LDS-staged) fused with atomic-free fill_csr ----
    gemm_l1_fill<<<3128 * 3, 256, 0, stream>>>(X1b, Wl1s, Wr1s, bl1, T1b, A1b, N,
                                               src, dst, endoff, rank, csr, E);

    // ---- Layer 2: gather (half-wave/node) then GEMM ----
    agg256_b<<<(N * 32 + 255) / 256, 256, 0, stream>>>(endoff, csr, T1b, A1b, X2b, N, E);
    gemm_bf16<<<dim3(2, (N + 127) / 128), 256, 0, stream>>>(X2b, Wl2s, Wr2s, bl2,
                                                            T2b, A2b, N, 128);

    // ---- Layer 3: fused agg128 + gemv, then final scalar aggregation ----
    agg_gemv3<<<(N * 32 + 255) / 256, 256, 0, stream>>>(endoff, csr, T2b, A2b,
                                                        Wl3, Wr3, bl3, t3, out, N, E);
    agg1<<<(N + 255) / 256, 256, 0, stream>>>(endoff, csr, t3, out, N, E);
}

// Round 5
// 540.598 us; speedup vs baseline: 1.1429x; 1.0095x over previous
//
#include <hip/hip_runtime.h>
#include <hip/hip_bf16.h>

// GraphSAGE 3-layer, N=100000, E=1.6M, dims 256->256->128->1.
// R15: gather restructure in agg256_b / agg_gemv3. Each half-wave loads up
// to 32 neighbor indices with ONE coalesced csr[base+lane] load, then
// distributes them via __shfl (no memory). Row loads issue 16-deep
// back-to-back, removing the per-iteration (index-load -> row-load)
// latency serialization seen in R14 (agg256_b 120us @ 3.87TB/s, 48% peak,
// VALUBusy 29% => latency-bound). All other kernels unchanged from R14.

typedef __attribute__((ext_vector_type(8))) short short8;
typedef __attribute__((ext_vector_type(4))) float f32x4;

__device__ __forceinline__ unsigned short f2b(float f) {
    __hip_bfloat16 h = __float2bfloat16(f);
    return *reinterpret_cast<unsigned short*>(&h);
}
__device__ __forceinline__ float b2f(unsigned short u) {
    union { unsigned int i; float f; } v; v.i = ((unsigned int)u) << 16; return v.f;
}

__device__ __forceinline__ void gload_lds16(const unsigned short* g, unsigned short* l) {
    __builtin_amdgcn_global_load_lds(
        (const __attribute__((address_space(1))) unsigned int*)(const void*)g,
        (__attribute__((address_space(3))) unsigned int*)(void*)l,
        16, 0, 0);
}

// ---- fused prep: (convert_x + 64 edges) | prep_w x4 ----------------------
__global__ __launch_bounds__(256) void prep_fused(
    const float* __restrict__ x, unsigned short* __restrict__ xb,
    const float* __restrict__ Wl1, const float* __restrict__ Wr1,
    const float* __restrict__ Wl2, const float* __restrict__ Wr2,
    unsigned short* __restrict__ Wl1s, unsigned short* __restrict__ Wr1s,
    unsigned short* __restrict__ Wl2s, unsigned short* __restrict__ Wr2s,
    const int* __restrict__ dst, int* __restrict__ deg,
    unsigned short* __restrict__ rank, int E)
{
    const int b = blockIdx.x;
    const int tid = threadIdx.x;
    if (b < 25000) {
        const int i = b * 256 + tid;
        float4 v = *(const float4*)(x + (size_t)i * 4);
        ushort4 o;
        o.x = f2b(v.x); o.y = f2b(v.y); o.z = f2b(v.z); o.w = f2b(v.w);
        *(ushort4*)(xb + (size_t)i * 4) = o;
        if (tid < 64) {
            const int e = b * 64 + tid;
            if (e < E) rank[e] = (unsigned short)atomicAdd(&deg[dst[e]], 1);
        }
    } else {
        const float* W; unsigned short* O; int base, hs;
        if (b < 25256)      { W = Wl1; O = Wl1s; base = b - 25000; hs = 8; }
        else if (b < 25512) { W = Wr1; O = Wr1s; base = b - 25256; hs = 8; }
        else if (b < 25640) { W = Wl2; O = Wl2s; base = b - 25512; hs = 7; }
        else                { W = Wr2; O = Wr2s; base = b - 25640; hs = 7; }
        const int i = base * 256 + tid;
        const int k = i >> hs;
        const int h = i & ((1 << hs) - 1);
        O[((size_t)(((k >> 3) << hs) + h) << 3) + (k & 7)] = f2b(W[i]);
    }
}

// ---- scan ----------------------------------------------------------------
__global__ __launch_bounds__(256) void scan_phaseA(int* __restrict__ a,
                                                   int* __restrict__ blockSums, int n) {
    __shared__ int sh[256];
    const int tid = threadIdx.x;
    const int base = blockIdx.x * 1024 + tid * 4;
    int v[4];
    #pragma unroll
    for (int i = 0; i < 4; ++i) v[i] = (base + i < n) ? a[base + i] : 0;
    int tsum = v[0] + v[1] + v[2] + v[3];
    sh[tid] = tsum;
    __syncthreads();
    for (int off = 1; off < 256; off <<= 1) {
        int t = (tid >= off) ? sh[tid - off] : 0;
        __syncthreads();
        sh[tid] += t;
        __syncthreads();
    }
    int run = sh[tid] - tsum;
    #pragma unroll
    for (int i = 0; i < 4; ++i) {
        if (base + i < n) a[base + i] = run;
        run += v[i];
    }
    if (tid == 255) blockSums[blockIdx.x] = sh[255];
}

__global__ __launch_bounds__(256) void scan_phaseB(int* __restrict__ bs, int nb) {
    __shared__ int sh[256];
    const int tid = threadIdx.x;
    int v = (tid < nb) ? bs[tid] : 0;
    sh[tid] = v;
    __syncthreads();
    for (int off = 1; off < 256; off <<= 1) {
        int t = (tid >= off) ? sh[tid - off] : 0;
        __syncthreads();
        sh[tid] += t;
        __syncthreads();
    }
    if (tid < nb) bs[tid] = sh[tid] - v;
}

__global__ __launch_bounds__(256) void scan_phaseC(int* __restrict__ a,
                                                   const int* __restrict__ bs, int n) {
    const int base = blockIdx.x * 1024 + threadIdx.x * 4;
    const int add = bs[blockIdx.x];
    #pragma unroll
    for (int i = 0; i < 4; ++i)
        if (base + i < n) a[base + i] += add;
}

// ---- fused L1 GEMM (LDS-staged) + atomic-free fill_csr -------------------
__global__ __launch_bounds__(256) void gemm_l1_fill(
    const unsigned short* __restrict__ Xb,
    const unsigned short* __restrict__ Wsw_l,
    const unsigned short* __restrict__ Wsw_r,
    const float* __restrict__ bias,
    unsigned short* __restrict__ Tout,
    unsigned short* __restrict__ Abase,
    int M,
    const int* __restrict__ src, const int* __restrict__ dst,
    const int* __restrict__ starts, const unsigned short* __restrict__ rank,
    int* __restrict__ csr, int E)
{
    // bijective XCD swizzle: grid = 9384 = 8 * 1173
    const int bid = (blockIdx.x & 7) * 1173 + (blockIdx.x >> 3);
    const int grp = bid / 3;
    const int rem = bid - grp * 3;
    const int tid = threadIdx.x;

    if (rem != 0) {                        // fill_csr part: no atomics
        const int e = (grp * 2 + rem - 1) * 256 + tid;
        if (e < E) csr[starts[dst[e]] + (int)rank[e]] = src[e];
        return;
    }

    // ---- gemm part: 128 rows x 64 cols x {Wl,Wr}, K=256, BK=64 ----------
    __shared__ unsigned short smem[16384];

    const int wid = tid >> 6;
    const int lane = tid & 63;
    const int quad = lane >> 4;
    const int l15 = lane & 15;
    const int col0 = (grp & 3) << 6;
    const int m0 = (grp >> 2) * 128;

    const unsigned short* aSrc[4];
    unsigned int aOfs[4];
    #pragma unroll
    for (int i = 0; i < 4; ++i) {
        const int slot = i * 256 + tid;
        const int r = slot >> 3, cs = slot & 7;
        const int cg = cs ^ (r & 7);
        aSrc[i] = Xb + ((size_t)(m0 + r) << 8) + (cg << 3);
        aOfs[i] = (unsigned)((i * 256 + wid * 64) * 8);
    }
    const unsigned short* bSrc[4];
    unsigned int bOfs[4];
    #pragma unroll
    for (int i = 0; i < 4; ++i) {
        const int slot = i * 256 + tid;
        const int mat = slot >> 9, ko = (slot >> 6) & 7, col = slot & 63;
        const unsigned short* Wm = mat ? Wsw_r : Wsw_l;
        bSrc[i] = Wm + (((size_t)ko * 256 + col0 + col) << 3);
        bOfs[i] = (unsigned)(8192 + (i * 256 + wid * 64) * 8);
    }

    const f32x4 zero = {0.f, 0.f, 0.f, 0.f};
    f32x4 acc[2][8];
    #pragma unroll
    for (int mt = 0; mt < 2; ++mt)
        #pragma unroll
        for (int nt = 0; nt < 8; ++nt) acc[mt][nt] = zero;

    for (int ks = 0; ks < 4; ++ks) {
        #pragma unroll
        for (int i = 0; i < 4; ++i)
            gload_lds16(aSrc[i] + ks * 64, smem + aOfs[i]);
        #pragma unroll
        for (int i = 0; i < 4; ++i)
            gload_lds16(bSrc[i] + ks * 16384, smem + bOfs[i]);
        __syncthreads();

        #pragma unroll
        for (int k32 = 0; k32 < 2; ++k32) {
            short8 af[2], bf[8];
            #pragma unroll
            for (int mt = 0; mt < 2; ++mt) {
                const int row = wid * 32 + mt * 16 + l15;
                const int c = (k32 * 4 + quad) ^ (row & 7);
                af[mt] = *(const short8*)(smem + ((row << 3) + c) * 8);
            }
            #pragma unroll
            for (int nt = 0; nt < 4; ++nt) {
                const int colL = nt * 16 + l15;
                const int ko = k32 * 4 + quad;
                bf[nt]     = *(const short8*)(smem + 8192 + ((ko << 6) + colL) * 8);
                bf[nt + 4] = *(const short8*)(smem + 8192 + (512 + (ko << 6) + colL) * 8);
            }
            #pragma unroll
            for (int mt = 0; mt < 2; ++mt)
                #pragma unroll
                for (int nt = 0; nt < 8; ++nt)
                    acc[mt][nt] = __builtin_amdgcn_mfma_f32_16x16x32_bf16(
                        af[mt], bf[nt], acc[mt][nt], 0, 0, 0);
        }
        __syncthreads();
    }

    #pragma unroll
    for (int nt = 0; nt < 4; ++nt) {
        const int colg = col0 + nt * 16 + l15;
        const float bb = bias[colg];
        #pragma unroll
        for (int mt = 0; mt < 2; ++mt) {
            const int gmb = m0 + wid * 32 + mt * 16 + quad * 4;
            #pragma unroll
            for (int r = 0; r < 4; ++r) {
                if (gmb + r < M) {
                    Tout [(size_t)(gmb + r) * 256 + colg] = f2b(acc[mt][nt][r]);
                    Abase[(size_t)(gmb + r) * 256 + colg] = f2b(acc[mt][nt + 4][r] + bb);
                }
            }
        }
    }
}

// ---- layer-2 aggregation: half-wave/node, shfl-broadcast indices ---------
__global__ __launch_bounds__(256) void agg256_b(
    const int* __restrict__ endoff, const int* __restrict__ csr,
    const unsigned short* __restrict__ T,
    const unsigned short* __restrict__ Abase, unsigned short* __restrict__ Xout,
    int N, int E)
{
    const int node = (int)((blockIdx.x * 256 + threadIdx.x) >> 5);
    const int lane = threadIdx.x & 31;
    const int hsel = threadIdx.x & 32;     // half-of-wave64 selector for shfl
    if (node >= N) return;
    const int beg = endoff[node];
    const int end = (node + 1 < N) ? endoff[node + 1] : E;
    float s[8] = {0.f, 0.f, 0.f, 0.f, 0.f, 0.f, 0.f, 0.f};

    for (int base = beg; base < end; base += 32) {
        const int il = base + lane;
        const int vidx = csr[il < E ? il : (E - 1)];   // 32 indices / 1 load
        const int cnt = (end - base < 32) ? (end - base) : 32;
        int u = 0;
        for (; u + 16 <= cnt; u += 16) {
            short8 v[16];
            #pragma unroll
            for (int k = 0; k < 16; ++k) {
                const int r = __shfl(vidx, (u + k) | hsel, 64);
                v[k] = *(const short8*)(T + ((size_t)r << 8) + (lane << 3));
            }
            #pragma unroll
            for (int j = 0; j < 8; ++j) {
                float t0 = b2f((unsigned short)v[0][j])  + b2f((unsigned short)v[1][j]);
                float t1 = b2f((unsigned short)v[2][j])  + b2f((unsigned short)v[3][j]);
                float t2 = b2f((unsigned short)v[4][j])  + b2f((unsigned short)v[5][j]);
                float t3 = b2f((unsigned short)v[6][j])  + b2f((unsigned short)v[7][j]);
                float t4 = b2f((unsigned short)v[8][j])  + b2f((unsigned short)v[9][j]);
                float t5 = b2f((unsigned short)v[10][j]) + b2f((unsigned short)v[11][j]);
                float t6 = b2f((unsigned short)v[12][j]) + b2f((unsigned short)v[13][j]);
                float t7 = b2f((unsigned short)v[14][j]) + b2f((unsigned short)v[15][j]);
                s[j] += ((t0 + t1) + (t2 + t3)) + ((t4 + t5) + (t6 + t7));
            }
        }
        if (u + 8 <= cnt) {
            short8 v[8];
            #pragma unroll
            for (int k = 0; k < 8; ++k) {
                const int r = __shfl(vidx, (u + k) | hsel, 64);
                v[k] = *(const short8*)(T + ((size_t)r << 8) + (lane << 3));
            }
            #pragma unroll
            for (int j = 0; j < 8; ++j) {
                float t0 = b2f((unsigned short)v[0][j]) + b2f((unsigned short)v[1][j]);
                float t1 = b2f((unsigned short)v[2][j]) + b2f((unsigned short)v[3][j]);
                float t2 = b2f((unsigned short)v[4][j]) + b2f((unsigned short)v[5][j]);
                float t3 = b2f((unsigned short)v[6][j]) + b2f((unsigned short)v[7][j]);
                s[j] += (t0 + t1) + (t2 + t3);
            }
            u += 8;
        }
        for (; u < cnt; ++u) {
            const int r = __shfl(vidx, u | hsel, 64);
            const short8 v = *(const short8*)(T + ((size_t)r << 8) + (lane << 3));
            #pragma unroll
            for (int j = 0; j < 8; ++j) s[j] += b2f((unsigned short)v[j]);
        }
    }

    const float w = 1.0f / fmaxf((float)(end - beg), 1.0f);
    const short8 bu = *(const short8*)(Abase + ((size_t)node << 8) + (lane << 3));
    short8 o;
    #pragma unroll
    for (int j = 0; j < 8; ++j)
        o[j] = (short)f2b(fmaxf(b2f((unsigned short)bu[j]) + s[j] * w, 0.f));
    *(short8*)(Xout + ((size_t)node << 8) + (lane << 3)) = o;
}

// ---- standalone L2 GEMM (H=128, K=256) -----------------------------------
__global__ __launch_bounds__(256) void gemm_bf16(
    const unsigned short* __restrict__ Xb,
    const unsigned short* __restrict__ Wsw_l,
    const unsigned short* __restrict__ Wsw_r,
    const float* __restrict__ bias,
    unsigned short* __restrict__ Tout,
    unsigned short* __restrict__ Abase,
    int M, int H)
{
    const int tid = threadIdx.x;
    const int wid = tid >> 6;
    const int lane = tid & 63;
    const int quad = lane >> 4;
    const int l15 = lane & 15;

    const int col0 = blockIdx.x << 6;
    const int m0 = blockIdx.y * 128 + wid * 32;

    const unsigned short* aptr[2];
    #pragma unroll
    for (int mt = 0; mt < 2; ++mt) {
        int r = m0 + mt * 16 + l15;
        if (r > M - 1) r = M - 1;
        aptr[mt] = Xb + ((size_t)r << 8) + (quad << 3);
    }
    const unsigned short* bptr[8];
    #pragma unroll
    for (int nt = 0; nt < 4; ++nt) {
        const int col = col0 + nt * 16 + l15;
        bptr[nt]     = Wsw_l + (((size_t)quad * H + col) << 3);
        bptr[nt + 4] = Wsw_r + (((size_t)quad * H + col) << 3);
    }

    const f32x4 zero = {0.f, 0.f, 0.f, 0.f};
    f32x4 acc[2][8];
    #pragma unroll
    for (int mt = 0; mt < 2; ++mt)
        #pragma unroll
        for (int nt = 0; nt < 8; ++nt) acc[mt][nt] = zero;

    #pragma unroll 2
    for (int ks = 0; ks < 8; ++ks) {
        short8 af[2], bf[8];
        #pragma unroll
        for (int mt = 0; mt < 2; ++mt)
            af[mt] = *(const short8*)(aptr[mt] + ks * 32);
        #pragma unroll
        for (int nt = 0; nt < 8; ++nt)
            bf[nt] = *(const short8*)(bptr[nt] + (size_t)ks * 32 * H);
        #pragma unroll
        for (int mt = 0; mt < 2; ++mt)
            #pragma unroll
            for (int nt = 0; nt < 8; ++nt)
                acc[mt][nt] = __builtin_amdgcn_mfma_f32_16x16x32_bf16(
                    af[mt], bf[nt], acc[mt][nt], 0, 0, 0);
    }

    #pragma unroll
    for (int nt = 0; nt < 4; ++nt) {
        const int colg = col0 + nt * 16 + l15;
        const float bb = bias[colg];
        #pragma unroll
        for (int mt = 0; mt < 2; ++mt) {
            const int gmb = m0 + mt * 16 + quad * 4;
            #pragma unroll
            for (int r = 0; r < 4; ++r) {
                if (gmb + r < M) {
                    Tout [(size_t)(gmb + r) * H + colg] = f2b(acc[mt][nt][r]);
                    Abase[(size_t)(gmb + r) * H + colg] = f2b(acc[mt][nt + 4][r] + bb);
                }
            }
        }
    }
}

// ---- fused layer-3: agg128 + gemv, shfl-broadcast indices ----------------
__global__ __launch_bounds__(256) void agg_gemv3(
    const int* __restrict__ endoff, const int* __restrict__ csr,
    const unsigned short* __restrict__ T, const unsigned short* __restrict__ Ab,
    const float* __restrict__ Wl, const float* __restrict__ Wr,
    const float* __restrict__ b,
    float* __restrict__ t3, float* __restrict__ out, int N, int E)
{
    const int node = (int)((blockIdx.x * 256 + threadIdx.x) >> 5);
    const int lane = threadIdx.x & 31;
    const int hsel = threadIdx.x & 32;
    if (node >= N) return;
    const int beg = endoff[node];
    const int end = (node + 1 < N) ? endoff[node + 1] : E;
    float s0 = 0.f, s1 = 0.f, s2 = 0.f, s3 = 0.f;

    for (int base = beg; base < end; base += 32) {
        const int il = base + lane;
        const int vidx = csr[il < E ? il : (E - 1)];
        const int cnt = (end - base < 32) ? (end - base) : 32;
        int u = 0;
        for (; u + 16 <= cnt; u += 16) {
            ushort4 v[16];
            #pragma unroll
            for (int k = 0; k < 16; ++k) {
                const int r = __shfl(vidx, (u + k) | hsel, 64);
                v[k] = *(const ushort4*)(T + ((size_t)r << 7) + (lane << 2));
            }
            #pragma unroll
            for (int k = 0; k < 16; ++k) {
                s0 += b2f(v[k].x); s1 += b2f(v[k].y);
                s2 += b2f(v[k].z); s3 += b2f(v[k].w);
            }
        }
        if (u + 8 <= cnt) {
            ushort4 v[8];
            #pragma unroll
            for (int k = 0; k < 8; ++k) {
                const int r = __shfl(vidx, (u + k) | hsel, 64);
                v[k] = *(const ushort4*)(T + ((size_t)r << 7) + (lane << 2));
            }
            #pragma unroll
            for (int k = 0; k < 8; ++k) {
                s0 += b2f(v[k].x); s1 += b2f(v[k].y);
                s2 += b2f(v[k].z); s3 += b2f(v[k].w);
            }
            u += 8;
        }
        for (; u < cnt; ++u) {
            const int r = __shfl(vidx, u | hsel, 64);
            const ushort4 v = *(const ushort4*)(T + ((size_t)r << 7) + (lane << 2));
            s0 += b2f(v.x); s1 += b2f(v.y); s2 += b2f(v.z); s3 += b2f(v.w);
        }
    }

    const float w = 1.0f / fmaxf((float)(end - beg), 1.0f);
    const ushort4 bu = *(const ushort4*)(Ab + ((size_t)node << 7) + (lane << 2));
    const float h0 = fmaxf(b2f(bu.x) + s0 * w, 0.f);
    const float h1 = fmaxf(b2f(bu.y) + s1 * w, 0.f);
    const float h2 = fmaxf(b2f(bu.z) + s2 * w, 0.f);
    const float h3 = fmaxf(b2f(bu.w) + s3 * w, 0.f);

    const float4 wl = *(const float4*)(Wl + (lane << 2));
    const float4 wr = *(const float4*)(Wr + (lane << 2));
    float dl = h0 * wl.x + h1 * wl.y + h2 * wl.z + h3 * wl.w;
    float dr = h0 * wr.x + h1 * wr.y + h2 * wr.z + h3 * wr.w;
    #pragma unroll
    for (int off = 16; off > 0; off >>= 1) {
        dl += __shfl_down(dl, off, 64);
        dr += __shfl_down(dr, off, 64);
    }
    if (lane == 0) {
        t3[node] = dl;
        out[node] = dr + b[0];
    }
}

__global__ __launch_bounds__(256) void agg1(
    const int* __restrict__ endoff, const int* __restrict__ csr,
    const float* __restrict__ t3, float* __restrict__ out, int N, int E)
{
    const int i = blockIdx.x * blockDim.x + threadIdx.x;
    if (i >= N) return;
    const int beg = endoff[i];
    const int end = (i + 1 < N) ? endoff[i + 1] : E;
    int p = beg;
    float s = 0.f;
    for (; p + 4 <= end; p += 4)
        s += (t3[csr[p]] + t3[csr[p + 1]]) + (t3[csr[p + 2]] + t3[csr[p + 3]]);
    for (; p < end; ++p) s += t3[csr[p]];
    out[i] += s / fmaxf((float)(end - beg), 1.0f);
}

extern "C" void kernel_launch(void* const* d_in, const int* in_sizes, int n_in,
                              void* d_out, int out_size, void* d_ws, size_t ws_size,
                              hipStream_t stream) {
    const float* x   = (const float*)d_in[0];
    const int*   ei  = (const int*)d_in[1];
    const float* Wl1 = (const float*)d_in[2];
    const float* bl1 = (const float*)d_in[3];
    const float* Wr1 = (const float*)d_in[4];
    const float* Wl2 = (const float*)d_in[5];
    const float* bl2 = (const float*)d_in[6];
    const float* Wr2 = (const float*)d_in[7];
    const float* Wl3 = (const float*)d_in[8];
    const float* bl3 = (const float*)d_in[9];
    const float* Wr3 = (const float*)d_in[10];
    float* out = (float*)d_out;

    const int N = in_sizes[0] / 256;   // 100000
    const int E = in_sizes[1] / 2;     // 1600000
    const int* src = ei;
    const int* dst = ei + E;

    // ---- workspace layout, race-free aliasing ----------------------------
    char* W = (char*)d_ws;
    const size_t MB512 = (size_t)100000 * 512;   // 51.2MB
    unsigned short* X1b = (unsigned short*)(W);
    unsigned short* T1b = (unsigned short*)(W + MB512);
    unsigned short* A1b = (unsigned short*)(W + 2 * MB512);
    unsigned short* X2b = (unsigned short*)(W);                  // over dead X1b
    unsigned short* T2b = (unsigned short*)(W + MB512);          // over dead T1b
    unsigned short* A2b = (unsigned short*)(W + MB512 + MB512 / 2);
    char* S = W + 3 * MB512;                     // smalls @ 153.6M
    int*   endoff = (int*)(S);
    int*   bsums  = (int*)(S + (size_t)N * 4);
    float* t3     = (float*)(S + (size_t)N * 4 + 1024);
    int*   csr    = (int*)(S + (size_t)N * 8 + 1024);
    unsigned short* Wl1s = (unsigned short*)(S + (size_t)N * 8 + 1024 + (size_t)E * 4);
    unsigned short* Wr1s = Wl1s + 65536;
    unsigned short* Wl2s = Wr1s + 65536;
    unsigned short* Wr2s = Wl2s + 32768;
    unsigned short* rank = Wr2s + 32768;         // ushort[E], +3.2MB

    // ---- prep: fused conversions + interleaved degree count ----
    hipMemsetAsync(endoff, 0, (size_t)N * sizeof(int), stream);
    prep_fused<<<25768, 256, 0, stream>>>(
        x, X1b, Wl1, Wr1, Wl2, Wr2, Wl1s, Wr1s, Wl2s, Wr2s,
        dst, endoff, rank, E);
    const int nScanBlocks = (N + 1023) / 1024;
    scan_phaseA<<<nScanBlocks, 256, 0, stream>>>(endoff, bsums, N);
    scan_phaseB<<<1, 256, 0, stream>>>(bsums, nScanBlocks);
    scan_phaseC<<<nScanBlocks, 256, 0, stream>>>(endoff, bsums, N);

    // ---- Layer 1 GEMM (LDS-staged) fused with atomic-free fill_csr ----
    gemm_l1_fill<<<3128 * 3, 256, 0, stream>>>(X1b, Wl1s, Wr1s, bl1, T1b, A1b, N,
                                               src, dst, endoff, rank, csr, E);

    // ---- Layer 2: gather (half-wave/node) then GEMM ----
    agg256_b<<<(N * 32 + 255) / 256, 256, 0, stream>>>(endoff, csr, T1b, A1b, X2b, N, E);
    gemm_bf16<<<dim3(2, (N + 127) / 128), 256, 0, stream>>>(X2b, Wl2s, Wr2s, bl2,
                                                            T2b, A2b, N, 128);

    // ---- Layer 3: fused agg128 + gemv, then final scalar aggregation ----
    agg_gemv3<<<(N * 32 + 255) / 256, 256, 0, stream>>>(endoff, csr, T2b, A2b,
                                                        Wl3, Wr3, bl3, t3, out, N, E);
    agg1<<<(N + 255) / 256, 256, 0, stream>>>(endoff, csr, t3, out, N, E);
}

// Round 7
// 494.099 us; speedup vs baseline: 1.2505x; 1.0941x over previous
//
#include <hip/hip_runtime.h>
#include <hip/hip_bf16.h>

// GraphSAGE 3-layer, N=100000, E=1.6M, dims 256->256->128->1.
// R17: R16 (fp8 e4m3 T1b to break agg256_b's 402MB XCD-replication
// FETCH floor) reimplemented with gfx950 HARDWARE fp8 conversions:
// v_cvt_f32_fp8 (decode, 1 VALU op/elem) and v_cvt_pk_fp8_f32 (encode,
// saturating). No hip_fp8.h dependency. All else identical to R15/R16:
// LDS-staged L1 GEMM + atomic-free fill, shfl-broadcast gathers,
// interleaved prep, scan, L2 GEMM, fused L3.

typedef __attribute__((ext_vector_type(8))) short short8;
typedef __attribute__((ext_vector_type(4))) float f32x4;

__device__ __forceinline__ unsigned short f2b(float f) {
    __hip_bfloat16 h = __float2bfloat16(f);
    return *reinterpret_cast<unsigned short*>(&h);
}
__device__ __forceinline__ float b2f(unsigned short u) {
    union { unsigned int i; float f; } v; v.i = ((unsigned int)u) << 16; return v.f;
}
// fp8 e4m3 (OCP on gfx950) via hardware cvt
__device__ __forceinline__ unsigned char f2q(float f) {
    unsigned int p = __builtin_amdgcn_cvt_pk_fp8_f32(f, f, 0u, false);
    return (unsigned char)(p & 0xffu);
}

__device__ __forceinline__ void gload_lds16(const unsigned short* g, unsigned short* l) {
    __builtin_amdgcn_global_load_lds(
        (const __attribute__((address_space(1))) unsigned int*)(const void*)g,
        (__attribute__((address_space(3))) unsigned int*)(void*)l,
        16, 0, 0);
}

// accumulate 8 fp8 bytes (uint2) into s[0..7] with hardware decode
__device__ __forceinline__ void acc_fp8x8(const uint2 v, float* s) {
    s[0] += __builtin_amdgcn_cvt_f32_fp8(v.x, 0);
    s[1] += __builtin_amdgcn_cvt_f32_fp8(v.x, 1);
    s[2] += __builtin_amdgcn_cvt_f32_fp8(v.x, 2);
    s[3] += __builtin_amdgcn_cvt_f32_fp8(v.x, 3);
    s[4] += __builtin_amdgcn_cvt_f32_fp8(v.y, 0);
    s[5] += __builtin_amdgcn_cvt_f32_fp8(v.y, 1);
    s[6] += __builtin_amdgcn_cvt_f32_fp8(v.y, 2);
    s[7] += __builtin_amdgcn_cvt_f32_fp8(v.y, 3);
}

// ---- fused prep: (convert_x + 64 edges) | prep_w x4 ----------------------
__global__ __launch_bounds__(256) void prep_fused(
    const float* __restrict__ x, unsigned short* __restrict__ xb,
    const float* __restrict__ Wl1, const float* __restrict__ Wr1,
    const float* __restrict__ Wl2, const float* __restrict__ Wr2,
    unsigned short* __restrict__ Wl1s, unsigned short* __restrict__ Wr1s,
    unsigned short* __restrict__ Wl2s, unsigned short* __restrict__ Wr2s,
    const int* __restrict__ dst, int* __restrict__ deg,
    unsigned short* __restrict__ rank, int E)
{
    const int b = blockIdx.x;
    const int tid = threadIdx.x;
    if (b < 25000) {
        const int i = b * 256 + tid;
        float4 v = *(const float4*)(x + (size_t)i * 4);
        ushort4 o;
        o.x = f2b(v.x); o.y = f2b(v.y); o.z = f2b(v.z); o.w = f2b(v.w);
        *(ushort4*)(xb + (size_t)i * 4) = o;
        if (tid < 64) {
            const int e = b * 64 + tid;
            if (e < E) rank[e] = (unsigned short)atomicAdd(&deg[dst[e]], 1);
        }
    } else {
        const float* W; unsigned short* O; int base, hs;
        if (b < 25256)      { W = Wl1; O = Wl1s; base = b - 25000; hs = 8; }
        else if (b < 25512) { W = Wr1; O = Wr1s; base = b - 25256; hs = 8; }
        else if (b < 25640) { W = Wl2; O = Wl2s; base = b - 25512; hs = 7; }
        else                { W = Wr2; O = Wr2s; base = b - 25640; hs = 7; }
        const int i = base * 256 + tid;
        const int k = i >> hs;
        const int h = i & ((1 << hs) - 1);
        O[((size_t)(((k >> 3) << hs) + h) << 3) + (k & 7)] = f2b(W[i]);
    }
}

// ---- scan ----------------------------------------------------------------
__global__ __launch_bounds__(256) void scan_phaseA(int* __restrict__ a,
                                                   int* __restrict__ blockSums, int n) {
    __shared__ int sh[256];
    const int tid = threadIdx.x;
    const int base = blockIdx.x * 1024 + tid * 4;
    int v[4];
    #pragma unroll
    for (int i = 0; i < 4; ++i) v[i] = (base + i < n) ? a[base + i] : 0;
    int tsum = v[0] + v[1] + v[2] + v[3];
    sh[tid] = tsum;
    __syncthreads();
    for (int off = 1; off < 256; off <<= 1) {
        int t = (tid >= off) ? sh[tid - off] : 0;
        __syncthreads();
        sh[tid] += t;
        __syncthreads();
    }
    int run = sh[tid] - tsum;
    #pragma unroll
    for (int i = 0; i < 4; ++i) {
        if (base + i < n) a[base + i] = run;
        run += v[i];
    }
    if (tid == 255) blockSums[blockIdx.x] = sh[255];
}

__global__ __launch_bounds__(256) void scan_phaseB(int* __restrict__ bs, int nb) {
    __shared__ int sh[256];
    const int tid = threadIdx.x;
    int v = (tid < nb) ? bs[tid] : 0;
    sh[tid] = v;
    __syncthreads();
    for (int off = 1; off < 256; off <<= 1) {
        int t = (tid >= off) ? sh[tid - off] : 0;
        __syncthreads();
        sh[tid] += t;
        __syncthreads();
    }
    if (tid < nb) bs[tid] = sh[tid] - v;
}

__global__ __launch_bounds__(256) void scan_phaseC(int* __restrict__ a,
                                                   const int* __restrict__ bs, int n) {
    const int base = blockIdx.x * 1024 + threadIdx.x * 4;
    const int add = bs[blockIdx.x];
    #pragma unroll
    for (int i = 0; i < 4; ++i)
        if (base + i < n) a[base + i] += add;
}

// ---- fused L1 GEMM (LDS-staged, fp8 Tout) + atomic-free fill_csr ---------
__global__ __launch_bounds__(256) void gemm_l1_fill(
    const unsigned short* __restrict__ Xb,
    const unsigned short* __restrict__ Wsw_l,
    const unsigned short* __restrict__ Wsw_r,
    const float* __restrict__ bias,
    unsigned char* __restrict__ Tout,          // fp8 e4m3 [N][256]
    unsigned short* __restrict__ Abase,
    int M,
    const int* __restrict__ src, const int* __restrict__ dst,
    const int* __restrict__ starts, const unsigned short* __restrict__ rank,
    int* __restrict__ csr, int E)
{
    // bijective XCD swizzle: grid = 9384 = 8 * 1173
    const int bid = (blockIdx.x & 7) * 1173 + (blockIdx.x >> 3);
    const int grp = bid / 3;
    const int rem = bid - grp * 3;
    const int tid = threadIdx.x;

    if (rem != 0) {                        // fill_csr part: no atomics
        const int e = (grp * 2 + rem - 1) * 256 + tid;
        if (e < E) csr[starts[dst[e]] + (int)rank[e]] = src[e];
        return;
    }

    // ---- gemm part: 128 rows x 64 cols x {Wl,Wr}, K=256, BK=64 ----------
    __shared__ unsigned short smem[16384];

    const int wid = tid >> 6;
    const int lane = tid & 63;
    const int quad = lane >> 4;
    const int l15 = lane & 15;
    const int col0 = (grp & 3) << 6;
    const int m0 = (grp >> 2) * 128;

    const unsigned short* aSrc[4];
    unsigned int aOfs[4];
    #pragma unroll
    for (int i = 0; i < 4; ++i) {
        const int slot = i * 256 + tid;
        const int r = slot >> 3, cs = slot & 7;
        const int cg = cs ^ (r & 7);
        aSrc[i] = Xb + ((size_t)(m0 + r) << 8) + (cg << 3);
        aOfs[i] = (unsigned)((i * 256 + wid * 64) * 8);
    }
    const unsigned short* bSrc[4];
    unsigned int bOfs[4];
    #pragma unroll
    for (int i = 0; i < 4; ++i) {
        const int slot = i * 256 + tid;
        const int mat = slot >> 9, ko = (slot >> 6) & 7, col = slot & 63;
        const unsigned short* Wm = mat ? Wsw_r : Wsw_l;
        bSrc[i] = Wm + (((size_t)ko * 256 + col0 + col) << 3);
        bOfs[i] = (unsigned)(8192 + (i * 256 + wid * 64) * 8);
    }

    const f32x4 zero = {0.f, 0.f, 0.f, 0.f};
    f32x4 acc[2][8];
    #pragma unroll
    for (int mt = 0; mt < 2; ++mt)
        #pragma unroll
        for (int nt = 0; nt < 8; ++nt) acc[mt][nt] = zero;

    for (int ks = 0; ks < 4; ++ks) {
        #pragma unroll
        for (int i = 0; i < 4; ++i)
            gload_lds16(aSrc[i] + ks * 64, smem + aOfs[i]);
        #pragma unroll
        for (int i = 0; i < 4; ++i)
            gload_lds16(bSrc[i] + ks * 16384, smem + bOfs[i]);
        __syncthreads();

        #pragma unroll
        for (int k32 = 0; k32 < 2; ++k32) {
            short8 af[2], bf[8];
            #pragma unroll
            for (int mt = 0; mt < 2; ++mt) {
                const int row = wid * 32 + mt * 16 + l15;
                const int c = (k32 * 4 + quad) ^ (row & 7);
                af[mt] = *(const short8*)(smem + ((row << 3) + c) * 8);
            }
            #pragma unroll
            for (int nt = 0; nt < 4; ++nt) {
                const int colL = nt * 16 + l15;
                const int ko = k32 * 4 + quad;
                bf[nt]     = *(const short8*)(smem + 8192 + ((ko << 6) + colL) * 8);
                bf[nt + 4] = *(const short8*)(smem + 8192 + (512 + (ko << 6) + colL) * 8);
            }
            #pragma unroll
            for (int mt = 0; mt < 2; ++mt)
                #pragma unroll
                for (int nt = 0; nt < 8; ++nt)
                    acc[mt][nt] = __builtin_amdgcn_mfma_f32_16x16x32_bf16(
                        af[mt], bf[nt], acc[mt][nt], 0, 0, 0);
        }
        __syncthreads();
    }

    #pragma unroll
    for (int nt = 0; nt < 4; ++nt) {
        const int colg = col0 + nt * 16 + l15;
        const float bb = bias[colg];
        #pragma unroll
        for (int mt = 0; mt < 2; ++mt) {
            const int gmb = m0 + wid * 32 + mt * 16 + quad * 4;
            #pragma unroll
            for (int r = 0; r < 4; ++r) {
                if (gmb + r < M) {
                    Tout [(size_t)(gmb + r) * 256 + colg] = f2q(acc[mt][nt][r]);
                    Abase[(size_t)(gmb + r) * 256 + colg] = f2b(acc[mt][nt + 4][r] + bb);
                }
            }
        }
    }
}

// ---- layer-2 aggregation: half-wave/node, fp8 rows (256B), shfl idx ------
__global__ __launch_bounds__(256) void agg256_b(
    const int* __restrict__ endoff, const int* __restrict__ csr,
    const unsigned char* __restrict__ T,       // fp8 e4m3 [N][256]
    const unsigned short* __restrict__ Abase, unsigned short* __restrict__ Xout,
    int N, int E)
{
    const int node = (int)((blockIdx.x * 256 + threadIdx.x) >> 5);
    const int lane = threadIdx.x & 31;
    const int hsel = threadIdx.x & 32;     // half-of-wave64 selector for shfl
    if (node >= N) return;
    const int beg = endoff[node];
    const int end = (node + 1 < N) ? endoff[node + 1] : E;
    float s[8] = {0.f, 0.f, 0.f, 0.f, 0.f, 0.f, 0.f, 0.f};

    for (int base = beg; base < end; base += 32) {
        const int il = base + lane;
        const int vidx = csr[il < E ? il : (E - 1)];   // 32 indices / 1 load
        const int cnt = (end - base < 32) ? (end - base) : 32;
        int u = 0;
        for (; u + 16 <= cnt; u += 16) {
            uint2 v[16];
            #pragma unroll
            for (int k = 0; k < 16; ++k) {
                const int r = __shfl(vidx, (u + k) | hsel, 64);
                v[k] = *(const uint2*)(T + ((size_t)r << 8) + (lane << 3));
            }
            #pragma unroll
            for (int k = 0; k < 16; ++k) acc_fp8x8(v[k], s);
        }
        if (u + 8 <= cnt) {
            uint2 v[8];
            #pragma unroll
            for (int k = 0; k < 8; ++k) {
                const int r = __shfl(vidx, (u + k) | hsel, 64);
                v[k] = *(const uint2*)(T + ((size_t)r << 8) + (lane << 3));
            }
            #pragma unroll
            for (int k = 0; k < 8; ++k) acc_fp8x8(v[k], s);
            u += 8;
        }
        for (; u < cnt; ++u) {
            const int r = __shfl(vidx, u | hsel, 64);
            const uint2 v = *(const uint2*)(T + ((size_t)r << 8) + (lane << 3));
            acc_fp8x8(v, s);
        }
    }

    const float w = 1.0f / fmaxf((float)(end - beg), 1.0f);
    const short8 bu = *(const short8*)(Abase + ((size_t)node << 8) + (lane << 3));
    short8 o;
    #pragma unroll
    for (int j = 0; j < 8; ++j)
        o[j] = (short)f2b(fmaxf(b2f((unsigned short)bu[j]) + s[j] * w, 0.f));
    *(short8*)(Xout + ((size_t)node << 8) + (lane << 3)) = o;
}

// ---- standalone L2 GEMM (H=128, K=256) -----------------------------------
__global__ __launch_bounds__(256) void gemm_bf16(
    const unsigned short* __restrict__ Xb,
    const unsigned short* __restrict__ Wsw_l,
    const unsigned short* __restrict__ Wsw_r,
    const float* __restrict__ bias,
    unsigned short* __restrict__ Tout,
    unsigned short* __restrict__ Abase,
    int M, int H)
{
    const int tid = threadIdx.x;
    const int wid = tid >> 6;
    const int lane = tid & 63;
    const int quad = lane >> 4;
    const int l15 = lane & 15;

    const int col0 = blockIdx.x << 6;
    const int m0 = blockIdx.y * 128 + wid * 32;

    const unsigned short* aptr[2];
    #pragma unroll
    for (int mt = 0; mt < 2; ++mt) {
        int r = m0 + mt * 16 + l15;
        if (r > M - 1) r = M - 1;
        aptr[mt] = Xb + ((size_t)r << 8) + (quad << 3);
    }
    const unsigned short* bptr[8];
    #pragma unroll
    for (int nt = 0; nt < 4; ++nt) {
        const int col = col0 + nt * 16 + l15;
        bptr[nt]     = Wsw_l + (((size_t)quad * H + col) << 3);
        bptr[nt + 4] = Wsw_r + (((size_t)quad * H + col) << 3);
    }

    const f32x4 zero = {0.f, 0.f, 0.f, 0.f};
    f32x4 acc[2][8];
    #pragma unroll
    for (int mt = 0; mt < 2; ++mt)
        #pragma unroll
        for (int nt = 0; nt < 8; ++nt) acc[mt][nt] = zero;

    #pragma unroll 2
    for (int ks = 0; ks < 8; ++ks) {
        short8 af[2], bf[8];
        #pragma unroll
        for (int mt = 0; mt < 2; ++mt)
            af[mt] = *(const short8*)(aptr[mt] + ks * 32);
        #pragma unroll
        for (int nt = 0; nt < 8; ++nt)
            bf[nt] = *(const short8*)(bptr[nt] + (size_t)ks * 32 * H);
        #pragma unroll
        for (int mt = 0; mt < 2; ++mt)
            #pragma unroll
            for (int nt = 0; nt < 8; ++nt)
                acc[mt][nt] = __builtin_amdgcn_mfma_f32_16x16x32_bf16(
                    af[mt], bf[nt], acc[mt][nt], 0, 0, 0);
    }

    #pragma unroll
    for (int nt = 0; nt < 4; ++nt) {
        const int colg = col0 + nt * 16 + l15;
        const float bb = bias[colg];
        #pragma unroll
        for (int mt = 0; mt < 2; ++mt) {
            const int gmb = m0 + mt * 16 + quad * 4;
            #pragma unroll
            for (int r = 0; r < 4; ++r) {
                if (gmb + r < M) {
                    Tout [(size_t)(gmb + r) * H + colg] = f2b(acc[mt][nt][r]);
                    Abase[(size_t)(gmb + r) * H + colg] = f2b(acc[mt][nt + 4][r] + bb);
                }
            }
        }
    }
}

// ---- fused layer-3: agg128 + gemv, shfl-broadcast indices ----------------
__global__ __launch_bounds__(256) void agg_gemv3(
    const int* __restrict__ endoff, const int* __restrict__ csr,
    const unsigned short* __restrict__ T, const unsigned short* __restrict__ Ab,
    const float* __restrict__ Wl, const float* __restrict__ Wr,
    const float* __restrict__ b,
    float* __restrict__ t3, float* __restrict__ out, int N, int E)
{
    const int node = (int)((blockIdx.x * 256 + threadIdx.x) >> 5);
    const int lane = threadIdx.x & 31;
    const int hsel = threadIdx.x & 32;
    if (node >= N) return;
    const int beg = endoff[node];
    const int end = (node + 1 < N) ? endoff[node + 1] : E;
    float s0 = 0.f, s1 = 0.f, s2 = 0.f, s3 = 0.f;

    for (int base = beg; base < end; base += 32) {
        const int il = base + lane;
        const int vidx = csr[il < E ? il : (E - 1)];
        const int cnt = (end - base < 32) ? (end - base) : 32;
        int u = 0;
        for (; u + 16 <= cnt; u += 16) {
            ushort4 v[16];
            #pragma unroll
            for (int k = 0; k < 16; ++k) {
                const int r = __shfl(vidx, (u + k) | hsel, 64);
                v[k] = *(const ushort4*)(T + ((size_t)r << 7) + (lane << 2));
            }
            #pragma unroll
            for (int k = 0; k < 16; ++k) {
                s0 += b2f(v[k].x); s1 += b2f(v[k].y);
                s2 += b2f(v[k].z); s3 += b2f(v[k].w);
            }
        }
        if (u + 8 <= cnt) {
            ushort4 v[8];
            #pragma unroll
            for (int k = 0; k < 8; ++k) {
                const int r = __shfl(vidx, (u + k) | hsel, 64);
                v[k] = *(const ushort4*)(T + ((size_t)r << 7) + (lane << 2));
            }
            #pragma unroll
            for (int k = 0; k < 8; ++k) {
                s0 += b2f(v[k].x); s1 += b2f(v[k].y);
                s2 += b2f(v[k].z); s3 += b2f(v[k].w);
            }
            u += 8;
        }
        for (; u < cnt; ++u) {
            const int r = __shfl(vidx, u | hsel, 64);
            const ushort4 v = *(const ushort4*)(T + ((size_t)r << 7) + (lane << 2));
            s0 += b2f(v.x); s1 += b2f(v.y); s2 += b2f(v.z); s3 += b2f(v.w);
        }
    }

    const float w = 1.0f / fmaxf((float)(end - beg), 1.0f);
    const ushort4 bu = *(const ushort4*)(Ab + ((size_t)node << 7) + (lane << 2));
    const float h0 = fmaxf(b2f(bu.x) + s0 * w, 0.f);
    const float h1 = fmaxf(b2f(bu.y) + s1 * w, 0.f);
    const float h2 = fmaxf(b2f(bu.z) + s2 * w, 0.f);
    const float h3 = fmaxf(b2f(bu.w) + s3 * w, 0.f);

    const float4 wl = *(const float4*)(Wl + (lane << 2));
    const float4 wr = *(const float4*)(Wr + (lane << 2));
    float dl = h0 * wl.x + h1 * wl.y + h2 * wl.z + h3 * wl.w;
    float dr = h0 * wr.x + h1 * wr.y + h2 * wr.z + h3 * wr.w;
    #pragma unroll
    for (int off = 16; off > 0; off >>= 1) {
        dl += __shfl_down(dl, off, 64);
        dr += __shfl_down(dr, off, 64);
    }
    if (lane == 0) {
        t3[node] = dl;
        out[node] = dr + b[0];
    }
}

__global__ __launch_bounds__(256) void agg1(
    const int* __restrict__ endoff, const int* __restrict__ csr,
    const float* __restrict__ t3, float* __restrict__ out, int N, int E)
{
    const int i = blockIdx.x * blockDim.x + threadIdx.x;
    if (i >= N) return;
    const int beg = endoff[i];
    const int end = (i + 1 < N) ? endoff[i + 1] : E;
    int p = beg;
    float s = 0.f;
    for (; p + 4 <= end; p += 4)
        s += (t3[csr[p]] + t3[csr[p + 1]]) + (t3[csr[p + 2]] + t3[csr[p + 3]]);
    for (; p < end; ++p) s += t3[csr[p]];
    out[i] += s / fmaxf((float)(end - beg), 1.0f);
}

extern "C" void kernel_launch(void* const* d_in, const int* in_sizes, int n_in,
                              void* d_out, int out_size, void* d_ws, size_t ws_size,
                              hipStream_t stream) {
    const float* x   = (const float*)d_in[0];
    const int*   ei  = (const int*)d_in[1];
    const float* Wl1 = (const float*)d_in[2];
    const float* bl1 = (const float*)d_in[3];
    const float* Wr1 = (const float*)d_in[4];
    const float* Wl2 = (const float*)d_in[5];
    const float* bl2 = (const float*)d_in[6];
    const float* Wr2 = (const float*)d_in[7];
    const float* Wl3 = (const float*)d_in[8];
    const float* bl3 = (const float*)d_in[9];
    const float* Wr3 = (const float*)d_in[10];
    float* out = (float*)d_out;

    const int N = in_sizes[0] / 256;   // 100000
    const int E = in_sizes[1] / 2;     // 1600000
    const int* src = ei;
    const int* dst = ei + E;

    // ---- workspace layout, race-free aliasing ----------------------------
    //   prep:       W X1b[0,51.2), rank, deg
    //   L1+fill:    R X1b,rank,starts  W T1b(fp8)[51.2,76.8) A1b[102.4,153.6) csr
    //   agg256_b:   R T1b,A1b,csr      W X2b[0,51.2)          (X1b dead)
    //   gemm_l2:    R X2b              W T2b[51.2,76.8) A2b[76.8,102.4)
    //                                  (T1b dead; T2b overwrites it)
    //   agg_gemv3:  R T2b,A2b,csr      W t3,out               (X2b dead)
    //   agg1:       R t3,csr           RW out
    char* W = (char*)d_ws;
    const size_t MB512 = (size_t)100000 * 512;   // 51.2MB
    unsigned short* X1b = (unsigned short*)(W);
    unsigned char*  T1b = (unsigned char*)(W + MB512);           // fp8, 25.6MB
    unsigned short* A1b = (unsigned short*)(W + 2 * MB512);
    unsigned short* X2b = (unsigned short*)(W);                  // over dead X1b
    unsigned short* T2b = (unsigned short*)(W + MB512);          // over dead T1b
    unsigned short* A2b = (unsigned short*)(W + MB512 + MB512 / 2);
    char* S = W + 3 * MB512;                     // smalls @ 153.6M
    int*   endoff = (int*)(S);
    int*   bsums  = (int*)(S + (size_t)N * 4);
    float* t3     = (float*)(S + (size_t)N * 4 + 1024);
    int*   csr    = (int*)(S + (size_t)N * 8 + 1024);
    unsigned short* Wl1s = (unsigned short*)(S + (size_t)N * 8 + 1024 + (size_t)E * 4);
    unsigned short* Wr1s = Wl1s + 65536;
    unsigned short* Wl2s = Wr1s + 65536;
    unsigned short* Wr2s = Wl2s + 32768;
    unsigned short* rank = Wr2s + 32768;         // ushort[E], +3.2MB

    // ---- prep: fused conversions + interleaved degree count ----
    hipMemsetAsync(endoff, 0, (size_t)N * sizeof(int), stream);
    prep_fused<<<25768, 256, 0, stream>>>(
        x, X1b, Wl1, Wr1, Wl2, Wr2, Wl1s, Wr1s, Wl2s, Wr2s,
        dst, endoff, rank, E);
    const int nScanBlocks = (N + 1023) / 1024;
    scan_phaseA<<<nScanBlocks, 256, 0, stream>>>(endoff, bsums, N);
    scan_phaseB<<<1, 256, 0, stream>>>(bsums, nScanBlocks);
    scan_phaseC<<<nScanBlocks, 256, 0, stream>>>(endoff, bsums, N);

    // ---- Layer 1 GEMM (LDS-staged, fp8 T) fused with atomic-free fill ----
    gemm_l1_fill<<<3128 * 3, 256, 0, stream>>>(X1b, Wl1s, Wr1s, bl1, T1b, A1b, N,
                                               src, dst, endoff, rank, csr, E);

    // ---- Layer 2: gather (half-wave/node, fp8 rows) then GEMM ----
    agg256_b<<<(N * 32 + 255) / 256, 256, 0, stream>>>(endoff, csr, T1b, A1b, X2b, N, E);
    gemm_bf16<<<dim3(2, (N + 127) / 128), 256, 0, stream>>>(X2b, Wl2s, Wr2s, bl2,
                                                            T2b, A2b, N, 128);

    // ---- Layer 3: fused agg128 + gemv, then final scalar aggregation ----
    agg_gemv3<<<(N * 32 + 255) / 256, 256, 0, stream>>>(endoff, csr, T2b, A2b,
                                                        Wl3, Wr3, bl3, t3, out, N, E);
    agg1<<<(N + 255) / 256, 256, 0, stream>>>(endoff, csr, t3, out, N, E);
}